// Round 2
// baseline (4622.698 us; speedup 1.0000x reference)
//
#include <hip/hip_runtime.h>
#include <math.h>

#define CI   700
#define TIN  300
#define DD   25
#define TOUT 276
#define BB   64
#define OINH 128
#define OEXC 256

// ---------------------------------------------------------------------------
// Build DCLS kernels; output layout kt[(i*25+d)*O + o]  (pre-transposed so the
// conv kernel can stage LDS with coalesced float4 copies, no transpose).
// ---------------------------------------------------------------------------
__global__ void build_kt(const float* __restrict__ W, const float* __restrict__ P,
                         const float* __restrict__ SIG, float* __restrict__ kt, int O) {
    int n = blockIdx.x * 256 + threadIdx.x;
    if (n >= O * CI) return;
    int o = n % O;          // o fastest -> coalesced kt writes
    int i = n / O;
    float w   = fabsf(W[o * CI + i]);
    float p   = fminf(fmaxf(P[o * CI + i], -12.f), 12.f) + 12.f;   // lim = 25//2
    float sig = fabsf(SIG[o * CI + i]) + 0.27f;
    float inv = 1.f / sig;
    float g[DD];
    float sum = 0.f;
#pragma unroll
    for (int d = 0; d < DD; ++d) {
        float e = ((float)d - p) * inv;
        g[d] = expf(-0.5f * e * e);
        sum += g[d];
    }
    float sc = w / (sum + 1e-7f);
#pragma unroll
    for (int d = 0; d < DD; ++d)
        kt[(i * DD + d) * O + o] = g[d] * sc;
}

// ---------------------------------------------------------------------------
// Pre-negate/abs/transpose w_exc_inh: wt[c*256 + o] = -|w[o*128 + c]|
// ---------------------------------------------------------------------------
__global__ void wt_kernel(const float* __restrict__ w, float* __restrict__ wt) {
    int n = blockIdx.x * 256 + threadIdx.x;
    if (n >= OINH * OEXC) return;
    int o = n % OEXC, c = n / OEXC;
    wt[c * OEXC + o] = -fabsf(w[o * OINH + c]);
}

// ---------------------------------------------------------------------------
// VALID conv, implicit GEMM. out[b,o,t] = sum_{i,d} x[b,i,t+d]*k[o,i,d]
// Block tile: 128 o x 64 t, 256 threads, per-thread 4o x 8t.
// i-chunks of 4 (175 chunks, 700 = 175*4 exactly).
// ---------------------------------------------------------------------------
__global__ __launch_bounds__(256)
void conv_dcls(const float* __restrict__ x, const float* __restrict__ kt,
               float* __restrict__ out, int O) {
    __shared__ float k_lds[100 * 128];   // [j=ic*25+d][o'] 51.2 KB
    __shared__ float x_lds[4 * 88];      // [ic][t0..t0+87]  1.4 KB

    const int tid = threadIdx.x;
    const int tx = tid & 7;              // 8 t-groups  -> t = t0 + tx*8 + rt
    const int ty = tid >> 3;             // 32 o-groups -> o = o0 + ty*4 + ro
    const int b  = blockIdx.z;
    const int t0 = blockIdx.x * 64;
    const int o0 = blockIdx.y * 128;
    const int tlim = TIN - t0;           // valid x length from t0 (always %4==0)

    float acc[4][8];
#pragma unroll
    for (int ro = 0; ro < 4; ++ro)
#pragma unroll
        for (int rt = 0; rt < 8; ++rt) acc[ro][rt] = 0.f;

    for (int chunk = 0; chunk < 175; ++chunk) {
        const int i0 = chunk * 4;
        __syncthreads();                 // protect LDS from previous compute
        // --- stage k tile: 100 rows x 128 o = 3200 float4, coalesced ---
#pragma unroll
        for (int s = 0; s < 13; ++s) {
            int f = tid + s * 256;
            if (f < 3200) {
                int j = f >> 5, o4 = f & 31;
                ((float4*)k_lds)[f] =
                    *(const float4*)(kt + (size_t)(i0 * DD + j) * O + o0 + o4 * 4);
            }
        }
        // --- stage x tile: 4 rows x 88 = 88 float4 ---
        if (tid < 88) {
            int ic = tid / 22, wq = tid % 22;
            float4 v = make_float4(0.f, 0.f, 0.f, 0.f);
            if (wq * 4 < tlim)
                v = *(const float4*)(x + (size_t)(b * CI + i0 + ic) * TIN + t0 + wq * 4);
            ((float4*)x_lds)[tid] = v;
        }
        __syncthreads();
        // --- compute ---
#pragma unroll
        for (int ic = 0; ic < 4; ++ic) {
            float xv[32];
#pragma unroll
            for (int wq = 0; wq < 8; ++wq)
                *(float4*)(xv + 4 * wq) = ((const float4*)(x_lds + ic * 88))[tx * 2 + wq];
#pragma unroll
            for (int d = 0; d < DD; ++d) {
                float4 kv = ((const float4*)(k_lds + (ic * DD + d) * 128))[ty];
                float kvv[4] = {kv.x, kv.y, kv.z, kv.w};
#pragma unroll
                for (int ro = 0; ro < 4; ++ro)
#pragma unroll
                    for (int rt = 0; rt < 8; ++rt)
                        acc[ro][rt] += kvv[ro] * xv[rt + d];
            }
        }
    }
    // --- write (float4 pairs, guarded for last t-tile: 276-256=20, %4==0) ---
    const int tvalid = TOUT - t0;
#pragma unroll
    for (int ro = 0; ro < 4; ++ro) {
        float* op = out + (size_t)(b * O + o0 + ty * 4 + ro) * TOUT + t0;
#pragma unroll
        for (int u = 0; u < 2; ++u) {
            int toff = tx * 8 + u * 4;
            if (toff < tvalid) {
                float4 v = make_float4(acc[ro][u * 4 + 0], acc[ro][u * 4 + 1],
                                       acc[ro][u * 4 + 2], acc[ro][u * 4 + 3]);
                *(float4*)(op + toff) = v;
            }
        }
    }
}

// ---------------------------------------------------------------------------
// BN training stats per channel over (B, T'): scale/shift form.
// ---------------------------------------------------------------------------
__global__ void bn_stats(const float* __restrict__ cinh, const float* __restrict__ gamma,
                         const float* __restrict__ beta, float* __restrict__ scale,
                         float* __restrict__ shift) {
    const int c = blockIdx.x, tid = threadIdx.x;
    float sum = 0.f, sq = 0.f;
    for (int idx = tid; idx < BB * TOUT; idx += 256) {
        int b = idx / TOUT, t = idx - b * TOUT;
        float v = cinh[(size_t)(b * OINH + c) * TOUT + t];
        sum += v; sq += v * v;
    }
#pragma unroll
    for (int off = 32; off; off >>= 1) {
        sum += __shfl_down(sum, off);
        sq  += __shfl_down(sq, off);
    }
    __shared__ float ls[8];
    int wid = tid >> 6;
    if ((tid & 63) == 0) { ls[wid * 2] = sum; ls[wid * 2 + 1] = sq; }
    __syncthreads();
    if (tid == 0) {
        float S = 0.f, Q = 0.f;
#pragma unroll
        for (int wv = 0; wv < 4; ++wv) { S += ls[wv * 2]; Q += ls[wv * 2 + 1]; }
        const float n = (float)(BB * TOUT);
        float mean = S / n;
        float var  = Q / n - mean * mean;          // biased (ddof=0), as jnp.var
        float rs   = 1.f / sqrtf(var + 1e-5f);
        float sc   = gamma[c] * rs;
        scale[c] = sc;
        shift[c] = beta[c] - mean * sc;
    }
}

// ---------------------------------------------------------------------------
// LIF: sequential over t. v = 0.5 v + x; spike = (v >= 1); hard reset.
// spikes layout (t, b, c) for the downstream GEMM.
// ---------------------------------------------------------------------------
__global__ void lif_kernel(const float* __restrict__ cinh, const float* __restrict__ scale,
                           const float* __restrict__ shift, float* __restrict__ spk) {
    const int b = blockIdx.x, c = threadIdx.x;
    const float sc = scale[c], sh = shift[c];
    const float* row = cinh + (size_t)(b * OINH + c) * TOUT;
    float v = 0.f;
    for (int t = 0; t < TOUT; ++t) {
        float xin = row[t] * sc + sh;
        v = 0.5f * v + xin;
        float s = (v >= 1.f) ? 1.f : 0.f;
        spk[((size_t)t * BB + b) * OINH + c] = s;
        v = (v >= 1.f) ? 0.f : v;
    }
}

// ---------------------------------------------------------------------------
// out[b,o,t] += sum_c spk[t,b,c] * wt[c,o]   (RMW on excit already in d_out)
// Block tile 64 o x 64 t, 256 threads, per-thread 4x4. wt rows are L2-hot.
// ---------------------------------------------------------------------------
__global__ __launch_bounds__(256)
void finale(const float* __restrict__ spk, const float* __restrict__ wt,
            float* __restrict__ out) {
    __shared__ float s_lds[64 * 129];    // [tt][c], pad 129 -> conflict-free
    const int tid = threadIdx.x;
    const int tx = tid & 15, ty = tid >> 4;
    const int b = blockIdx.z, t0 = blockIdx.x * 64, o0 = blockIdx.y * 64;

#pragma unroll
    for (int s = 0; s < 32; ++s) {
        int f = tid + s * 256;           // 8192 = 64*128
        int tt = f >> 7, c = f & 127;
        float v = 0.f;
        if (t0 + tt < TOUT) v = spk[((size_t)(t0 + tt) * BB + b) * OINH + c];
        s_lds[tt * 129 + c] = v;
    }
    __syncthreads();

    float acc[4][4] = {{0.f}};
#pragma unroll 4
    for (int c = 0; c < 128; ++c) {
        float4 wv = *(const float4*)(wt + c * OEXC + o0 + ty * 4);
        float wvv[4] = {wv.x, wv.y, wv.z, wv.w};
        float sv[4];
#pragma unroll
        for (int rt = 0; rt < 4; ++rt) sv[rt] = s_lds[(tx * 4 + rt) * 129 + c];
#pragma unroll
        for (int ro = 0; ro < 4; ++ro)
#pragma unroll
            for (int rt = 0; rt < 4; ++rt)
                acc[ro][rt] += wvv[ro] * sv[rt];
    }

    const int tvalid = TOUT - t0;
    if (tx * 4 < tvalid) {
#pragma unroll
        for (int ro = 0; ro < 4; ++ro) {
            float* op = out + (size_t)(b * OEXC + o0 + ty * 4 + ro) * TOUT + t0 + tx * 4;
            float4 v = *(float4*)op;
            v.x += acc[ro][0]; v.y += acc[ro][1]; v.z += acc[ro][2]; v.w += acc[ro][3];
            *(float4*)op = v;
        }
    }
}

// ---------------------------------------------------------------------------
extern "C" void kernel_launch(void* const* d_in, const int* in_sizes, int n_in,
                              void* d_out, int out_size, void* d_ws, size_t ws_size,
                              hipStream_t stream) {
    const float* x       = (const float*)d_in[0];
    const float* W_inh   = (const float*)d_in[1];
    const float* P_inh   = (const float*)d_in[2];
    const float* SIG_inh = (const float*)d_in[3];
    const float* W_exc   = (const float*)d_in[4];
    const float* P_exc   = (const float*)d_in[5];
    const float* SIG_exc = (const float*)d_in[6];
    const float* w_ei    = (const float*)d_in[7];
    const float* gamma   = (const float*)d_in[8];
    const float* beta    = (const float*)d_in[9];
    float* out = (float*)d_out;
    float* ws  = (float*)d_ws;

    float* kt_exc = ws;                          // 17500*256 = 4,480,000
    float* kt_inh = kt_exc + 4480000;            // 17500*128 = 2,240,000
    float* cinh   = kt_inh + 2240000;            // 64*128*276 = 2,260,992
    float* spk    = cinh   + 2260992;            // 276*64*128 = 2,260,992
    float* scale  = spk    + 2260992;            // 128
    float* shift  = scale  + 128;                // 128
    float* wt     = shift  + 128;                // 128*256 = 32,768  (total ~45 MB)

    hipLaunchKernelGGL(build_kt, dim3(700), dim3(256), 0, stream, W_exc, P_exc, SIG_exc, kt_exc, OEXC);
    hipLaunchKernelGGL(build_kt, dim3(350), dim3(256), 0, stream, W_inh, P_inh, SIG_inh, kt_inh, OINH);
    hipLaunchKernelGGL(wt_kernel, dim3(128), dim3(256), 0, stream, w_ei, wt);

    hipLaunchKernelGGL(conv_dcls, dim3(5, 2, 64), dim3(256), 0, stream, x, kt_exc, out,  OEXC);
    hipLaunchKernelGGL(conv_dcls, dim3(5, 1, 64), dim3(256), 0, stream, x, kt_inh, cinh, OINH);

    hipLaunchKernelGGL(bn_stats,   dim3(128), dim3(256), 0, stream, cinh, gamma, beta, scale, shift);
    hipLaunchKernelGGL(lif_kernel, dim3(64),  dim3(128), 0, stream, cinh, scale, shift, spk);
    hipLaunchKernelGGL(finale,     dim3(5, 4, 64), dim3(256), 0, stream, spk, wt, out);
}

// Round 3
// 2153.562 us; speedup vs baseline: 2.1465x; 2.1465x over previous
//
#include <hip/hip_runtime.h>
#include <math.h>

#define CI   700
#define TIN  300
#define DD   25
#define TOUT 276
#define BB   64
#define OINH 128
#define OEXC 256

#define TROWS 312          // padded t-rows in xT (covers t0=192 block window 192..311)
#define IPAD  704          // channels padded to 11*64

typedef __attribute__((ext_vector_type(8))) short short8;
typedef __attribute__((ext_vector_type(4))) float f32x4;
typedef __attribute__((ext_vector_type(8))) unsigned short ushort8v;

static __device__ __forceinline__ unsigned short f2bf(float f) {
    unsigned int u = __float_as_uint(f);
    unsigned int r = (u + 0x7FFFu + ((u >> 16) & 1u)) >> 16;   // RNE
    return (unsigned short)r;
}

static __device__ __forceinline__ void gload_lds16(const void* g, void* l) {
    __builtin_amdgcn_global_load_lds(
        (const __attribute__((address_space(1))) unsigned int*)g,
        (__attribute__((address_space(3))) unsigned int*)l, 16, 0, 0);
}

// ---------------------------------------------------------------------------
// Inh path: build fp32 DCLS kernel, layout kt[(i*25+d)*OINH + o]
// ---------------------------------------------------------------------------
__global__ void build_kt(const float* __restrict__ W, const float* __restrict__ P,
                         const float* __restrict__ SIG, float* __restrict__ kt, int O) {
    int n = blockIdx.x * 256 + threadIdx.x;
    if (n >= O * CI) return;
    int o = n % O;
    int i = n / O;
    float w   = fabsf(W[o * CI + i]);
    float p   = fminf(fmaxf(P[o * CI + i], -12.f), 12.f) + 12.f;
    float sig = fabsf(SIG[o * CI + i]) + 0.27f;
    float inv = 1.f / sig;
    float g[DD];
    float sum = 0.f;
#pragma unroll
    for (int d = 0; d < DD; ++d) {
        float e = ((float)d - p) * inv;
        g[d] = expf(-0.5f * e * e);
        sum += g[d];
    }
    float sc = w / (sum + 1e-7f);
#pragma unroll
    for (int d = 0; d < DD; ++d)
        kt[(i * DD + d) * O + o] = g[d] * sc;
}

// ---------------------------------------------------------------------------
// Exc path: bf16 DCLS kernel, layout kb2[d][o][ipad] (i contiguous)
// ---------------------------------------------------------------------------
__global__ void kexc_build(const float* __restrict__ W, const float* __restrict__ P,
                           const float* __restrict__ SIG, unsigned short* __restrict__ kb2) {
    int n = blockIdx.x * 256 + threadIdx.x;           // n = o*IPAD + ip
    if (n >= OEXC * IPAD) return;
    int o = n / IPAD, ip = n % IPAD;
    if (ip >= CI) {
#pragma unroll
        for (int d = 0; d < DD; ++d)
            kb2[((size_t)d * OEXC + o) * IPAD + ip] = 0;
        return;
    }
    float w   = fabsf(W[o * CI + ip]);
    float p   = fminf(fmaxf(P[o * CI + ip], -12.f), 12.f) + 12.f;
    float sig = fabsf(SIG[o * CI + ip]) + 0.27f;
    float inv = 1.f / sig;
    float g[DD];
    float sum = 0.f;
#pragma unroll
    for (int d = 0; d < DD; ++d) {
        float e = ((float)d - p) * inv;
        g[d] = expf(-0.5f * e * e);
        sum += g[d];
    }
    float sc = w / (sum + 1e-7f);
#pragma unroll
    for (int d = 0; d < DD; ++d)
        kb2[((size_t)d * OEXC + o) * IPAD + ip] = f2bf(g[d] * sc);
}

// ---------------------------------------------------------------------------
// xT[b][t][ipad] bf16 = x[b][i][t], zero-padded t>=300 and i>=700.
// LDS transpose, 64x64 tiles. grid (5 tchunks, 11 ichunks, 64 b).
// ---------------------------------------------------------------------------
__global__ __launch_bounds__(256)
void xt_kernel(const float* __restrict__ x, unsigned short* __restrict__ xT) {
    __shared__ float tile[64][65];
    const int tid = threadIdx.x;
    const int t0 = blockIdx.x * 64, i0 = blockIdx.y * 64, b = blockIdx.z;
#pragma unroll
    for (int s = 0; s < 16; ++s) {
        int f = s * 256 + tid;
        int tt = f & 63, ii = f >> 6;
        float v = 0.f;
        if (t0 + tt < TIN && i0 + ii < CI)
            v = x[((size_t)b * CI + i0 + ii) * TIN + t0 + tt];
        tile[tt][ii] = v;
    }
    __syncthreads();
#pragma unroll
    for (int s = 0; s < 2; ++s) {
        int f = s * 256 + tid;
        int tt = f >> 3, g = f & 7;
        if (t0 + tt < TROWS) {
            ushort8v v;
#pragma unroll
            for (int e = 0; e < 8; ++e) v[e] = f2bf(tile[tt][g * 8 + e]);
            *(ushort8v*)(xT + ((size_t)b * TROWS + t0 + tt) * IPAD + i0 + g * 8) = v;
        }
    }
}

// ---------------------------------------------------------------------------
// Pre-negate/abs/transpose w_exc_inh: wt[c*256 + o] = -|w[o*128 + c]|
// ---------------------------------------------------------------------------
__global__ void wt_kernel(const float* __restrict__ w, float* __restrict__ wt) {
    int n = blockIdx.x * 256 + threadIdx.x;
    if (n >= OINH * OEXC) return;
    int o = n % OEXC, c = n / OEXC;
    wt[c * OEXC + o] = -fabsf(w[o * OINH + c]);
}

// ---------------------------------------------------------------------------
// Exc conv via MFMA bf16. Block = 128 thr = 2 waves (o-split), tile 128o x 96t.
// Wave: 64o x 96t = 4x6 tiles of 16x16, K-loop: 11 chunks of 64ch x 25 delays.
// LDS swizzle: 16B slot ^= (row&7), applied on global source (linear LDS dest).
// grid (3 t, 2 o, 64 b).
// ---------------------------------------------------------------------------
__global__ __launch_bounds__(128)
void conv_mfma(const unsigned short* __restrict__ xT, const unsigned short* __restrict__ kb2,
               float* __restrict__ out) {
    __shared__ unsigned short xs[120 * 64];        // [trow][ch] 15.36 KB, swizzled
    __shared__ unsigned short ks[2][2][64 * 64];   // [buf][wave][orow][ch] 32 KB

    const int tid  = threadIdx.x;
    const int wave = tid >> 6;
    const int lane = tid & 63;
    const int l15 = lane & 15, l4 = lane >> 4, l7 = lane & 7;
    const int b  = blockIdx.z;
    const int t0 = blockIdx.x * 96;
    const int o0 = blockIdx.y * 128 + wave * 64;   // this wave's global o base

    const int ld_row = lane >> 3;                  // staging: row within 8-row issue
    const int ld_swz = ((l7 ^ ld_row) << 4);       // pre-swizzled source column byte

    f32x4 acc[4][6];
#pragma unroll
    for (int i = 0; i < 4; ++i)
#pragma unroll
        for (int j = 0; j < 6; ++j) acc[i][j] = (f32x4)0.f;

    const char* xrow0 = (const char*)xT + ((size_t)b * TROWS + t0) * (IPAD * 2);

    for (int ic = 0; ic < 11; ++ic) {
        const int ic0 = ic * 64;
        __syncthreads();                           // xs about to be overwritten
        // stage x window: 120 rows x 128B, both waves cooperate (15 issues)
        for (int j = wave; j < 15; j += 2)
            gload_lds16(xrow0 + (size_t)(8 * j + ld_row) * (IPAD * 2) + ic0 * 2 + ld_swz,
                        (char*)xs + j * 1024);
        // stage k for d=0 into buf 0 (own 64 o rows, 8 issues)
        {
            const char* ksrc = (const char*)kb2 + ((size_t)o0) * (IPAD * 2) + ic0 * 2;
            char* kdst = (char*)ks + (0 * 2 + wave) * 8192;
#pragma unroll
            for (int j = 0; j < 8; ++j)
                gload_lds16(ksrc + (size_t)(8 * j + ld_row) * (IPAD * 2) + ld_swz,
                            kdst + j * 1024);
        }
        asm volatile("s_waitcnt vmcnt(0)" ::: "memory");
        __syncthreads();

        for (int d = 0; d < DD; ++d) {
            const int cur = d & 1;
            if (d < DD - 1) {                      // prefetch next delay's k-slice
                const char* ksrc = (const char*)kb2 +
                    ((size_t)(d + 1) * OEXC + o0) * (IPAD * 2) + ic0 * 2;
                char* kdst = (char*)ks + ((cur ^ 1) * 2 + wave) * 8192;
#pragma unroll
                for (int j = 0; j < 8; ++j)
                    gload_lds16(ksrc + (size_t)(8 * j + ld_row) * (IPAD * 2) + ld_swz,
                                kdst + j * 1024);
            }
            const char* kp = (const char*)ks + (cur * 2 + wave) * 8192;
#pragma unroll
            for (int ks2 = 0; ks2 < 2; ++ks2) {
                const int cg = ks2 * 4 + l4;
                short8 A[4];
#pragma unroll
                for (int i = 0; i < 4; ++i)
                    A[i] = *(const short8*)(kp + (i * 16 + l15) * 128 + ((cg ^ l7) << 4));
#pragma unroll
                for (int j = 0; j < 6; ++j) {
                    const int tr = j * 16 + l15 + d;
                    short8 Bv = *(const short8*)((const char*)xs + tr * 128 +
                                                 ((cg ^ (tr & 7)) << 4));
#pragma unroll
                    for (int i = 0; i < 4; ++i)
                        acc[i][j] = __builtin_amdgcn_mfma_f32_16x16x32_bf16(
                            A[i], Bv, acc[i][j], 0, 0, 0);
                }
            }
            asm volatile("s_waitcnt vmcnt(0)" ::: "memory");  // next-d k-slice landed
        }
    }

    // epilogue: D col = lane&15 (t), row = (lane>>4)*4 + reg (o)
#pragma unroll
    for (int i = 0; i < 4; ++i)
#pragma unroll
        for (int j = 0; j < 6; ++j) {
            const int tt = t0 + j * 16 + l15;
            if (tt < TOUT) {
                float* op = out + ((size_t)b * OEXC + o0 + i * 16 + l4 * 4) * TOUT + tt;
#pragma unroll
                for (int r = 0; r < 4; ++r) op[(size_t)r * TOUT] = acc[i][j][r];
            }
        }
}

// ---------------------------------------------------------------------------
// Inh conv fp32 (unchanged from passing round-2 kernel).
// Block tile: 128 o x 64 t, 256 threads, per-thread 4o x 8t.
// ---------------------------------------------------------------------------
__global__ __launch_bounds__(256)
void conv_dcls(const float* __restrict__ x, const float* __restrict__ kt,
               float* __restrict__ out, int O) {
    __shared__ float k_lds[100 * 128];
    __shared__ float x_lds[4 * 88];

    const int tid = threadIdx.x;
    const int tx = tid & 7;
    const int ty = tid >> 3;
    const int b  = blockIdx.z;
    const int t0 = blockIdx.x * 64;
    const int o0 = blockIdx.y * 128;
    const int tlim = TIN - t0;

    float acc[4][8];
#pragma unroll
    for (int ro = 0; ro < 4; ++ro)
#pragma unroll
        for (int rt = 0; rt < 8; ++rt) acc[ro][rt] = 0.f;

    for (int chunk = 0; chunk < 175; ++chunk) {
        const int i0 = chunk * 4;
        __syncthreads();
#pragma unroll
        for (int s = 0; s < 13; ++s) {
            int f = tid + s * 256;
            if (f < 3200) {
                int j = f >> 5, o4 = f & 31;
                ((float4*)k_lds)[f] =
                    *(const float4*)(kt + (size_t)(i0 * DD + j) * O + o0 + o4 * 4);
            }
        }
        if (tid < 88) {
            int icc = tid / 22, wq = tid % 22;
            float4 v = make_float4(0.f, 0.f, 0.f, 0.f);
            if (wq * 4 < tlim)
                v = *(const float4*)(x + (size_t)(b * CI + i0 + icc) * TIN + t0 + wq * 4);
            ((float4*)x_lds)[tid] = v;
        }
        __syncthreads();
#pragma unroll
        for (int icc = 0; icc < 4; ++icc) {
            float xv[32];
#pragma unroll
            for (int wq = 0; wq < 8; ++wq)
                *(float4*)(xv + 4 * wq) = ((const float4*)(x_lds + icc * 88))[tx * 2 + wq];
#pragma unroll
            for (int d = 0; d < DD; ++d) {
                float4 kv = ((const float4*)(k_lds + (icc * DD + d) * 128))[ty];
                float kvv[4] = {kv.x, kv.y, kv.z, kv.w};
#pragma unroll
                for (int ro = 0; ro < 4; ++ro)
#pragma unroll
                    for (int rt = 0; rt < 8; ++rt)
                        acc[ro][rt] += kvv[ro] * xv[rt + d];
            }
        }
    }
    const int tvalid = TOUT - t0;
#pragma unroll
    for (int ro = 0; ro < 4; ++ro) {
        float* op = out + (size_t)(b * O + o0 + ty * 4 + ro) * TOUT + t0;
#pragma unroll
        for (int u = 0; u < 2; ++u) {
            int toff = tx * 8 + u * 4;
            if (toff < tvalid) {
                float4 v = make_float4(acc[ro][u * 4 + 0], acc[ro][u * 4 + 1],
                                       acc[ro][u * 4 + 2], acc[ro][u * 4 + 3]);
                *(float4*)(op + toff) = v;
            }
        }
    }
}

// ---------------------------------------------------------------------------
// BN training stats per channel over (B, T'): scale/shift form.
// ---------------------------------------------------------------------------
__global__ void bn_stats(const float* __restrict__ cinh, const float* __restrict__ gamma,
                         const float* __restrict__ beta, float* __restrict__ scale,
                         float* __restrict__ shift) {
    const int c = blockIdx.x, tid = threadIdx.x;
    float sum = 0.f, sq = 0.f;
    for (int idx = tid; idx < BB * TOUT; idx += 256) {
        int b = idx / TOUT, t = idx - b * TOUT;
        float v = cinh[(size_t)(b * OINH + c) * TOUT + t];
        sum += v; sq += v * v;
    }
#pragma unroll
    for (int off = 32; off; off >>= 1) {
        sum += __shfl_down(sum, off);
        sq  += __shfl_down(sq, off);
    }
    __shared__ float ls[8];
    int wid = tid >> 6;
    if ((tid & 63) == 0) { ls[wid * 2] = sum; ls[wid * 2 + 1] = sq; }
    __syncthreads();
    if (tid == 0) {
        float S = 0.f, Q = 0.f;
#pragma unroll
        for (int wv = 0; wv < 4; ++wv) { S += ls[wv * 2]; Q += ls[wv * 2 + 1]; }
        const float n = (float)(BB * TOUT);
        float mean = S / n;
        float var  = Q / n - mean * mean;
        float rs   = 1.f / sqrtf(var + 1e-5f);
        float sc   = gamma[c] * rs;
        scale[c] = sc;
        shift[c] = beta[c] - mean * sc;
    }
}

// ---------------------------------------------------------------------------
// LIF: v = 0.5 v + x; spike = (v >= 1); hard reset. spikes (t, b, c).
// ---------------------------------------------------------------------------
__global__ void lif_kernel(const float* __restrict__ cinh, const float* __restrict__ scale,
                           const float* __restrict__ shift, float* __restrict__ spk) {
    const int b = blockIdx.x, c = threadIdx.x;
    const float sc = scale[c], sh = shift[c];
    const float* row = cinh + (size_t)(b * OINH + c) * TOUT;
    float v = 0.f;
    for (int t = 0; t < TOUT; ++t) {
        float xin = row[t] * sc + sh;
        v = 0.5f * v + xin;
        float s = (v >= 1.f) ? 1.f : 0.f;
        spk[((size_t)t * BB + b) * OINH + c] = s;
        v = (v >= 1.f) ? 0.f : v;
    }
}

// ---------------------------------------------------------------------------
// out[b,o,t] += sum_c spk[t,b,c] * wt[c,o]
// ---------------------------------------------------------------------------
__global__ __launch_bounds__(256)
void finale(const float* __restrict__ spk, const float* __restrict__ wt,
            float* __restrict__ out) {
    __shared__ float s_lds[64 * 129];
    const int tid = threadIdx.x;
    const int tx = tid & 15, ty = tid >> 4;
    const int b = blockIdx.z, t0 = blockIdx.x * 64, o0 = blockIdx.y * 64;

#pragma unroll
    for (int s = 0; s < 32; ++s) {
        int f = tid + s * 256;
        int tt = f >> 7, c = f & 127;
        float v = 0.f;
        if (t0 + tt < TOUT) v = spk[((size_t)(t0 + tt) * BB + b) * OINH + c];
        s_lds[tt * 129 + c] = v;
    }
    __syncthreads();

    float acc[4][4] = {{0.f}};
#pragma unroll 4
    for (int c = 0; c < 128; ++c) {
        float4 wv = *(const float4*)(wt + c * OEXC + o0 + ty * 4);
        float wvv[4] = {wv.x, wv.y, wv.z, wv.w};
        float sv[4];
#pragma unroll
        for (int rt = 0; rt < 4; ++rt) sv[rt] = s_lds[(tx * 4 + rt) * 129 + c];
#pragma unroll
        for (int ro = 0; ro < 4; ++ro)
#pragma unroll
            for (int rt = 0; rt < 4; ++rt)
                acc[ro][rt] += wvv[ro] * sv[rt];
    }

    const int tvalid = TOUT - t0;
    if (tx * 4 < tvalid) {
#pragma unroll
        for (int ro = 0; ro < 4; ++ro) {
            float* op = out + (size_t)(b * OEXC + o0 + ty * 4 + ro) * TOUT + t0 + tx * 4;
            float4 v = *(float4*)op;
            v.x += acc[ro][0]; v.y += acc[ro][1]; v.z += acc[ro][2]; v.w += acc[ro][3];
            *(float4*)op = v;
        }
    }
}

// ---------------------------------------------------------------------------
extern "C" void kernel_launch(void* const* d_in, const int* in_sizes, int n_in,
                              void* d_out, int out_size, void* d_ws, size_t ws_size,
                              hipStream_t stream) {
    const float* x       = (const float*)d_in[0];
    const float* W_inh   = (const float*)d_in[1];
    const float* P_inh   = (const float*)d_in[2];
    const float* SIG_inh = (const float*)d_in[3];
    const float* W_exc   = (const float*)d_in[4];
    const float* P_exc   = (const float*)d_in[5];
    const float* SIG_exc = (const float*)d_in[6];
    const float* w_ei    = (const float*)d_in[7];
    const float* gamma   = (const float*)d_in[8];
    const float* beta    = (const float*)d_in[9];
    float* out = (float*)d_out;

    // ws layout (bytes): xT bf16 | kb2 bf16 | fp32 scratch  (~64.3 MB total)
    unsigned short* xT  = (unsigned short*)d_ws;                        // 64*312*704
    unsigned short* kb2 = xT + (size_t)BB * TROWS * IPAD;               // 25*256*704
    float* fws   = (float*)(kb2 + (size_t)DD * OEXC * IPAD);
    float* kt_inh = fws;                          // 17500*128 = 2,240,000
    float* cinh   = kt_inh + 2240000;             // 64*128*276 = 2,260,992
    float* spk    = cinh   + 2260992;             // 276*64*128 = 2,260,992
    float* scale  = spk    + 2260992;             // 128
    float* shift  = scale  + 128;                 // 128
    float* wt     = shift  + 128;                 // 128*256

    // prep
    hipLaunchKernelGGL(kexc_build, dim3((OEXC * IPAD + 255) / 256), dim3(256), 0, stream,
                       W_exc, P_exc, SIG_exc, kb2);
    hipLaunchKernelGGL(build_kt, dim3(350), dim3(256), 0, stream,
                       W_inh, P_inh, SIG_inh, kt_inh, OINH);
    hipLaunchKernelGGL(xt_kernel, dim3(5, 11, 64), dim3(256), 0, stream, x, xT);
    hipLaunchKernelGGL(wt_kernel, dim3(128), dim3(256), 0, stream, w_ei, wt);

    // convs
    hipLaunchKernelGGL(conv_mfma, dim3(3, 2, 64), dim3(128), 0, stream, xT, kb2, out);
    hipLaunchKernelGGL(conv_dcls, dim3(5, 1, 64), dim3(256), 0, stream, x, kt_inh, cinh, OINH);

    // inh tail
    hipLaunchKernelGGL(bn_stats,   dim3(128), dim3(256), 0, stream, cinh, gamma, beta, scale, shift);
    hipLaunchKernelGGL(lif_kernel, dim3(64),  dim3(128), 0, stream, cinh, scale, shift, spk);
    hipLaunchKernelGGL(finale,     dim3(5, 4, 64), dim3(256), 0, stream, spk, wt, out);
}

// Round 4
// 634.203 us; speedup vs baseline: 7.2890x; 3.3957x over previous
//
#include <hip/hip_runtime.h>
#include <math.h>

#define CI   700
#define TIN  300
#define DD   25
#define TOUT 276
#define BB   64
#define OINH 128
#define OEXC 256

#define TROWS 312          // padded t-rows in xT
#define IPAD  704          // channels padded to 11*64

typedef __attribute__((ext_vector_type(8))) short short8;
typedef __attribute__((ext_vector_type(4))) float f32x4;
typedef __attribute__((ext_vector_type(8))) unsigned short ushort8v;

static __device__ __forceinline__ unsigned short f2bf(float f) {
    unsigned int u = __float_as_uint(f);
    unsigned int r = (u + 0x7FFFu + ((u >> 16) & 1u)) >> 16;   // RNE
    return (unsigned short)r;
}
static __device__ __forceinline__ float bf2f(unsigned short h) {
    return __uint_as_float(((unsigned int)h) << 16);
}

static __device__ __forceinline__ void gload_lds16(const void* g, void* l) {
    __builtin_amdgcn_global_load_lds(
        (const __attribute__((address_space(1))) unsigned int*)g,
        (__attribute__((address_space(3))) unsigned int*)l, 16, 0, 0);
}

// ---------------------------------------------------------------------------
// Fallback inh path: fp32 DCLS kernel, layout kt[(i*25+d)*OINH + o]
// ---------------------------------------------------------------------------
__global__ void build_kt(const float* __restrict__ W, const float* __restrict__ P,
                         const float* __restrict__ SIG, float* __restrict__ kt, int O) {
    int n = blockIdx.x * 256 + threadIdx.x;
    if (n >= O * CI) return;
    int o = n % O;
    int i = n / O;
    float w   = fabsf(W[o * CI + i]);
    float p   = fminf(fmaxf(P[o * CI + i], -12.f), 12.f) + 12.f;
    float sig = fabsf(SIG[o * CI + i]) + 0.27f;
    float inv = 1.f / sig;
    float g[DD];
    float sum = 0.f;
#pragma unroll
    for (int d = 0; d < DD; ++d) {
        float e = ((float)d - p) * inv;
        g[d] = expf(-0.5f * e * e);
        sum += g[d];
    }
    float sc = w / (sum + 1e-7f);
#pragma unroll
    for (int d = 0; d < DD; ++d)
        kt[(i * DD + d) * O + o] = g[d] * sc;
}

// ---------------------------------------------------------------------------
// Exc path: bf16 DCLS kernel (hi only), layout kb2[d][o][ipad]
// ---------------------------------------------------------------------------
__global__ void kexc_build(const float* __restrict__ W, const float* __restrict__ P,
                           const float* __restrict__ SIG, unsigned short* __restrict__ kb2) {
    int n = blockIdx.x * 256 + threadIdx.x;           // n = o*IPAD + ip
    if (n >= OEXC * IPAD) return;
    int o = n / IPAD, ip = n % IPAD;
    if (ip >= CI) {
#pragma unroll
        for (int d = 0; d < DD; ++d)
            kb2[((size_t)d * OEXC + o) * IPAD + ip] = 0;
        return;
    }
    float w   = fabsf(W[o * CI + ip]);
    float p   = fminf(fmaxf(P[o * CI + ip], -12.f), 12.f) + 12.f;
    float sig = fabsf(SIG[o * CI + ip]) + 0.27f;
    float inv = 1.f / sig;
    float g[DD];
    float sum = 0.f;
#pragma unroll
    for (int d = 0; d < DD; ++d) {
        float e = ((float)d - p) * inv;
        g[d] = expf(-0.5f * e * e);
        sum += g[d];
    }
    float sc = w / (sum + 1e-7f);
#pragma unroll
    for (int d = 0; d < DD; ++d)
        kb2[((size_t)d * OEXC + o) * IPAD + ip] = f2bf(g[d] * sc);
}

// ---------------------------------------------------------------------------
// Inh path (fast): split bf16 hi/lo DCLS kernel, layout [d][o][ipad] x2
// ---------------------------------------------------------------------------
__global__ void kinh_build(const float* __restrict__ W, const float* __restrict__ P,
                           const float* __restrict__ SIG,
                           unsigned short* __restrict__ kbh, unsigned short* __restrict__ kbl) {
    int n = blockIdx.x * 256 + threadIdx.x;           // n = o*IPAD + ip
    if (n >= OINH * IPAD) return;
    int o = n / IPAD, ip = n % IPAD;
    if (ip >= CI) {
#pragma unroll
        for (int d = 0; d < DD; ++d) {
            kbh[((size_t)d * OINH + o) * IPAD + ip] = 0;
            kbl[((size_t)d * OINH + o) * IPAD + ip] = 0;
        }
        return;
    }
    float w   = fabsf(W[o * CI + ip]);
    float p   = fminf(fmaxf(P[o * CI + ip], -12.f), 12.f) + 12.f;
    float sig = fabsf(SIG[o * CI + ip]) + 0.27f;
    float inv = 1.f / sig;
    float g[DD];
    float sum = 0.f;
#pragma unroll
    for (int d = 0; d < DD; ++d) {
        float e = ((float)d - p) * inv;
        g[d] = expf(-0.5f * e * e);
        sum += g[d];
    }
    float sc = w / (sum + 1e-7f);
#pragma unroll
    for (int d = 0; d < DD; ++d) {
        float v = g[d] * sc;
        unsigned short h = f2bf(v);
        kbh[((size_t)d * OINH + o) * IPAD + ip] = h;
        kbl[((size_t)d * OINH + o) * IPAD + ip] = f2bf(v - bf2f(h));
    }
}

// ---------------------------------------------------------------------------
// xT[b][t][ipad] bf16 hi (+optional lo) = x[b][i][t]. LDS transpose, 64x64.
// grid (5 tchunks, 11 ichunks, 64 b).
// ---------------------------------------------------------------------------
__global__ __launch_bounds__(256)
void xt_kernel(const float* __restrict__ x, unsigned short* __restrict__ xTh,
               unsigned short* __restrict__ xTl) {
    __shared__ float tile[64][65];
    const int tid = threadIdx.x;
    const int t0 = blockIdx.x * 64, i0 = blockIdx.y * 64, b = blockIdx.z;
#pragma unroll
    for (int s = 0; s < 16; ++s) {
        int f = s * 256 + tid;
        int tt = f & 63, ii = f >> 6;
        float v = 0.f;
        if (t0 + tt < TIN && i0 + ii < CI)
            v = x[((size_t)b * CI + i0 + ii) * TIN + t0 + tt];
        tile[tt][ii] = v;
    }
    __syncthreads();
#pragma unroll
    for (int s = 0; s < 2; ++s) {
        int f = s * 256 + tid;
        int tt = f >> 3, g = f & 7;
        if (t0 + tt < TROWS) {
            ushort8v vh, vl;
#pragma unroll
            for (int e = 0; e < 8; ++e) {
                float v = tile[tt][g * 8 + e];
                unsigned short h = f2bf(v);
                vh[e] = h;
                vl[e] = f2bf(v - bf2f(h));
            }
            size_t off = ((size_t)b * TROWS + t0 + tt) * IPAD + i0 + g * 8;
            *(ushort8v*)(xTh + off) = vh;
            if (xTl) *(ushort8v*)(xTl + off) = vl;
        }
    }
}

// ---------------------------------------------------------------------------
// wt[c*256 + o] = -|w[o*128 + c]|
// ---------------------------------------------------------------------------
__global__ void wt_kernel(const float* __restrict__ w, float* __restrict__ wt) {
    int n = blockIdx.x * 256 + threadIdx.x;
    if (n >= OINH * OEXC) return;
    int o = n % OEXC, c = n / OEXC;
    wt[c * OEXC + o] = -fabsf(w[o * OINH + c]);
}

// ---------------------------------------------------------------------------
// Exc conv via MFMA bf16 (round-3 kernel, unchanged). grid (3, 2, 64), 128 thr.
// ---------------------------------------------------------------------------
__global__ __launch_bounds__(128)
void conv_mfma(const unsigned short* __restrict__ xTh, const unsigned short* __restrict__ kb2,
               float* __restrict__ out) {
    __shared__ unsigned short xs[120 * 64];
    __shared__ unsigned short ks[2][2][64 * 64];

    const int tid  = threadIdx.x;
    const int wave = tid >> 6;
    const int lane = tid & 63;
    const int l15 = lane & 15, l4 = lane >> 4, l7 = lane & 7;
    const int b  = blockIdx.z;
    const int t0 = blockIdx.x * 96;
    const int o0 = blockIdx.y * 128 + wave * 64;

    const int ld_row = lane >> 3;
    const int ld_swz = ((l7 ^ ld_row) << 4);

    f32x4 acc[4][6];
#pragma unroll
    for (int i = 0; i < 4; ++i)
#pragma unroll
        for (int j = 0; j < 6; ++j) acc[i][j] = (f32x4)0.f;

    const char* xrow0 = (const char*)xTh + ((size_t)b * TROWS + t0) * (IPAD * 2);

    for (int ic = 0; ic < 11; ++ic) {
        const int ic0 = ic * 64;
        __syncthreads();
        for (int j = wave; j < 15; j += 2)
            gload_lds16(xrow0 + (size_t)(8 * j + ld_row) * (IPAD * 2) + ic0 * 2 + ld_swz,
                        (char*)xs + j * 1024);
        {
            const char* ksrc = (const char*)kb2 + ((size_t)o0) * (IPAD * 2) + ic0 * 2;
            char* kdst = (char*)ks + (0 * 2 + wave) * 8192;
#pragma unroll
            for (int j = 0; j < 8; ++j)
                gload_lds16(ksrc + (size_t)(8 * j + ld_row) * (IPAD * 2) + ld_swz,
                            kdst + j * 1024);
        }
        asm volatile("s_waitcnt vmcnt(0)" ::: "memory");
        __syncthreads();

        for (int d = 0; d < DD; ++d) {
            const int cur = d & 1;
            if (d < DD - 1) {
                const char* ksrc = (const char*)kb2 +
                    ((size_t)(d + 1) * OEXC + o0) * (IPAD * 2) + ic0 * 2;
                char* kdst = (char*)ks + ((cur ^ 1) * 2 + wave) * 8192;
#pragma unroll
                for (int j = 0; j < 8; ++j)
                    gload_lds16(ksrc + (size_t)(8 * j + ld_row) * (IPAD * 2) + ld_swz,
                                kdst + j * 1024);
            }
            const char* kp = (const char*)ks + (cur * 2 + wave) * 8192;
#pragma unroll
            for (int ks2 = 0; ks2 < 2; ++ks2) {
                const int cg = ks2 * 4 + l4;
                short8 A[4];
#pragma unroll
                for (int i = 0; i < 4; ++i)
                    A[i] = *(const short8*)(kp + (i * 16 + l15) * 128 + ((cg ^ l7) << 4));
#pragma unroll
                for (int j = 0; j < 6; ++j) {
                    const int tr = j * 16 + l15 + d;
                    short8 Bv = *(const short8*)((const char*)xs + tr * 128 +
                                                 ((cg ^ (tr & 7)) << 4));
#pragma unroll
                    for (int i = 0; i < 4; ++i)
                        acc[i][j] = __builtin_amdgcn_mfma_f32_16x16x32_bf16(
                            A[i], Bv, acc[i][j], 0, 0, 0);
                }
            }
            asm volatile("s_waitcnt vmcnt(0)" ::: "memory");
        }
    }

#pragma unroll
    for (int i = 0; i < 4; ++i)
#pragma unroll
        for (int j = 0; j < 6; ++j) {
            const int tt = t0 + j * 16 + l15;
            if (tt < TOUT) {
                float* op = out + ((size_t)b * OEXC + o0 + i * 16 + l4 * 4) * TOUT + tt;
#pragma unroll
                for (int r = 0; r < 4; ++r) op[(size_t)r * TOUT] = acc[i][j][r];
            }
        }
}

// ---------------------------------------------------------------------------
// Inh conv via split-bf16 MFMA (3 terms: kh*xh + kh*xl + kl*xh).
// Block = 128 thr = 2 waves t-split (48t each), 64 o per block.
// grid (3 t, 2 o, 64 b). Per-d: wave0 prefetches kh, wave1 kl; barrier per d.
// ---------------------------------------------------------------------------
__global__ __launch_bounds__(128)
void conv_mfma_inh(const unsigned short* __restrict__ xTh, const unsigned short* __restrict__ xTl,
                   const unsigned short* __restrict__ kbh, const unsigned short* __restrict__ kbl,
                   float* __restrict__ cinh) {
    __shared__ unsigned short xsh[120 * 64];       // 15.36 KB
    __shared__ unsigned short xsl[120 * 64];       // 15.36 KB
    __shared__ unsigned short ksh[2][64 * 64];     // 16.4 KB (dbuf)
    __shared__ unsigned short ksl[2][64 * 64];     // 16.4 KB

    const int tid  = threadIdx.x;
    const int wave = tid >> 6;
    const int lane = tid & 63;
    const int l15 = lane & 15, l4 = lane >> 4, l7 = lane & 7;
    const int b  = blockIdx.z;
    const int t0 = blockIdx.x * 96;
    const int o0 = blockIdx.y * 64;
    const int wtb = wave * 48;                     // wave's t sub-base within block

    const int ld_row = lane >> 3;
    const int ld_swz = ((l7 ^ ld_row) << 4);

    f32x4 acc[4][3];
#pragma unroll
    for (int i = 0; i < 4; ++i)
#pragma unroll
        for (int j = 0; j < 3; ++j) acc[i][j] = (f32x4)0.f;

    const char* xrh = (const char*)xTh + ((size_t)b * TROWS + t0) * (IPAD * 2);
    const char* xrl = (const char*)xTl + ((size_t)b * TROWS + t0) * (IPAD * 2);
    const unsigned short* kb = wave ? kbl : kbh;

    for (int ic = 0; ic < 11; ++ic) {
        const int ic0 = ic * 64;
        __syncthreads();                           // LDS about to be overwritten
        // stage x window hi+lo: 15 issues each, split across waves
        for (int j = wave; j < 15; j += 2) {
            gload_lds16(xrh + (size_t)(8 * j + ld_row) * (IPAD * 2) + ic0 * 2 + ld_swz,
                        (char*)xsh + j * 1024);
            gload_lds16(xrl + (size_t)(8 * j + ld_row) * (IPAD * 2) + ic0 * 2 + ld_swz,
                        (char*)xsl + j * 1024);
        }
        // stage k d=0 into buf0: wave0 -> ksh, wave1 -> ksl
        {
            char* kd = wave ? (char*)ksl[0] : (char*)ksh[0];
#pragma unroll
            for (int j = 0; j < 8; ++j)
                gload_lds16((const char*)kb +
                                ((size_t)(0 * OINH + o0 + 8 * j + ld_row)) * (IPAD * 2) +
                                ic0 * 2 + ld_swz,
                            kd + j * 1024);
        }
        asm volatile("s_waitcnt vmcnt(0)" ::: "memory");
        __syncthreads();

        for (int d = 0; d < DD; ++d) {
            const int cur = d & 1;
            if (d < DD - 1) {                      // prefetch next d (own array)
                char* kd = wave ? (char*)ksl[cur ^ 1] : (char*)ksh[cur ^ 1];
#pragma unroll
                for (int j = 0; j < 8; ++j)
                    gload_lds16((const char*)kb +
                                    ((size_t)((d + 1) * OINH + o0 + 8 * j + ld_row)) * (IPAD * 2) +
                                    ic0 * 2 + ld_swz,
                                kd + j * 1024);
            }
            const char* kph = (const char*)ksh[cur];
            const char* kpl = (const char*)ksl[cur];
#pragma unroll
            for (int k2 = 0; k2 < 2; ++k2) {
                const int cg = k2 * 4 + l4;
                short8 Ah[4], Al[4];
#pragma unroll
                for (int i = 0; i < 4; ++i) {
                    Ah[i] = *(const short8*)(kph + (i * 16 + l15) * 128 + ((cg ^ l7) << 4));
                    Al[i] = *(const short8*)(kpl + (i * 16 + l15) * 128 + ((cg ^ l7) << 4));
                }
#pragma unroll
                for (int j = 0; j < 3; ++j) {
                    const int tr = wtb + j * 16 + l15 + d;
                    short8 Bh = *(const short8*)((const char*)xsh + tr * 128 +
                                                 ((cg ^ (tr & 7)) << 4));
                    short8 Bl = *(const short8*)((const char*)xsl + tr * 128 +
                                                 ((cg ^ (tr & 7)) << 4));
#pragma unroll
                    for (int i = 0; i < 4; ++i) {
                        acc[i][j] = __builtin_amdgcn_mfma_f32_16x16x32_bf16(
                            Ah[i], Bh, acc[i][j], 0, 0, 0);
                        acc[i][j] = __builtin_amdgcn_mfma_f32_16x16x32_bf16(
                            Ah[i], Bl, acc[i][j], 0, 0, 0);
                        acc[i][j] = __builtin_amdgcn_mfma_f32_16x16x32_bf16(
                            Al[i], Bh, acc[i][j], 0, 0, 0);
                    }
                }
            }
            asm volatile("s_waitcnt vmcnt(0)" ::: "memory");  // next-d k landed
            __syncthreads();                       // cross-wave ksh/ksl visibility
        }
    }

    // epilogue: D col=lane&15 (t), row=(lane>>4)*4+reg (o)
#pragma unroll
    for (int i = 0; i < 4; ++i)
#pragma unroll
        for (int j = 0; j < 3; ++j) {
            const int tt = t0 + wtb + j * 16 + l15;
            if (tt < TOUT) {
                float* op = cinh + ((size_t)b * OINH + o0 + i * 16 + l4 * 4) * TOUT + tt;
#pragma unroll
                for (int r = 0; r < 4; ++r) op[(size_t)r * TOUT] = acc[i][j][r];
            }
        }
}

// ---------------------------------------------------------------------------
// Fallback inh conv fp32 (round-2/3 kernel, unchanged).
// ---------------------------------------------------------------------------
__global__ __launch_bounds__(256)
void conv_dcls(const float* __restrict__ x, const float* __restrict__ kt,
               float* __restrict__ out, int O) {
    __shared__ float k_lds[100 * 128];
    __shared__ float x_lds[4 * 88];

    const int tid = threadIdx.x;
    const int tx = tid & 7;
    const int ty = tid >> 3;
    const int b  = blockIdx.z;
    const int t0 = blockIdx.x * 64;
    const int o0 = blockIdx.y * 128;
    const int tlim = TIN - t0;

    float acc[4][8];
#pragma unroll
    for (int ro = 0; ro < 4; ++ro)
#pragma unroll
        for (int rt = 0; rt < 8; ++rt) acc[ro][rt] = 0.f;

    for (int chunk = 0; chunk < 175; ++chunk) {
        const int i0 = chunk * 4;
        __syncthreads();
#pragma unroll
        for (int s = 0; s < 13; ++s) {
            int f = tid + s * 256;
            if (f < 3200) {
                int j = f >> 5, o4 = f & 31;
                ((float4*)k_lds)[f] =
                    *(const float4*)(kt + (size_t)(i0 * DD + j) * O + o0 + o4 * 4);
            }
        }
        if (tid < 88) {
            int icc = tid / 22, wq = tid % 22;
            float4 v = make_float4(0.f, 0.f, 0.f, 0.f);
            if (wq * 4 < tlim)
                v = *(const float4*)(x + (size_t)(b * CI + i0 + icc) * TIN + t0 + wq * 4);
            ((float4*)x_lds)[tid] = v;
        }
        __syncthreads();
#pragma unroll
        for (int icc = 0; icc < 4; ++icc) {
            float xv[32];
#pragma unroll
            for (int wq = 0; wq < 8; ++wq)
                *(float4*)(xv + 4 * wq) = ((const float4*)(x_lds + icc * 88))[tx * 2 + wq];
#pragma unroll
            for (int d = 0; d < DD; ++d) {
                float4 kv = ((const float4*)(k_lds + (icc * DD + d) * 128))[ty];
                float kvv[4] = {kv.x, kv.y, kv.z, kv.w};
#pragma unroll
                for (int ro = 0; ro < 4; ++ro)
#pragma unroll
                    for (int rt = 0; rt < 8; ++rt)
                        acc[ro][rt] += kvv[ro] * xv[rt + d];
            }
        }
    }
    const int tvalid = TOUT - t0;
#pragma unroll
    for (int ro = 0; ro < 4; ++ro) {
        float* op = out + (size_t)(b * O + o0 + ty * 4 + ro) * TOUT + t0;
#pragma unroll
        for (int u = 0; u < 2; ++u) {
            int toff = tx * 8 + u * 4;
            if (toff < tvalid) {
                float4 v = make_float4(acc[ro][u * 4 + 0], acc[ro][u * 4 + 1],
                                       acc[ro][u * 4 + 2], acc[ro][u * 4 + 3]);
                *(float4*)(op + toff) = v;
            }
        }
    }
}

// ---------------------------------------------------------------------------
// BN training stats per channel over (B, T'): scale/shift form.
// ---------------------------------------------------------------------------
__global__ void bn_stats(const float* __restrict__ cinh, const float* __restrict__ gamma,
                         const float* __restrict__ beta, float* __restrict__ scale,
                         float* __restrict__ shift) {
    const int c = blockIdx.x, tid = threadIdx.x;
    float sum = 0.f, sq = 0.f;
    for (int idx = tid; idx < BB * TOUT; idx += 256) {
        int b = idx / TOUT, t = idx - b * TOUT;
        float v = cinh[(size_t)(b * OINH + c) * TOUT + t];
        sum += v; sq += v * v;
    }
#pragma unroll
    for (int off = 32; off; off >>= 1) {
        sum += __shfl_down(sum, off);
        sq  += __shfl_down(sq, off);
    }
    __shared__ float ls[8];
    int wid = tid >> 6;
    if ((tid & 63) == 0) { ls[wid * 2] = sum; ls[wid * 2 + 1] = sq; }
    __syncthreads();
    if (tid == 0) {
        float S = 0.f, Q = 0.f;
#pragma unroll
        for (int wv = 0; wv < 4; ++wv) { S += ls[wv * 2]; Q += ls[wv * 2 + 1]; }
        const float n = (float)(BB * TOUT);
        float mean = S / n;
        float var  = Q / n - mean * mean;
        float rs   = 1.f / sqrtf(var + 1e-5f);
        float sc   = gamma[c] * rs;
        scale[c] = sc;
        shift[c] = beta[c] - mean * sc;
    }
}

// ---------------------------------------------------------------------------
// LIF: v = 0.5 v + x; spike = (v >= 1); hard reset. spikes (t, b, c) as u8.
// ---------------------------------------------------------------------------
__global__ void lif_kernel(const float* __restrict__ cinh, const float* __restrict__ scale,
                           const float* __restrict__ shift, unsigned char* __restrict__ spk) {
    const int b = blockIdx.x, c = threadIdx.x;
    const float sc = scale[c], sh = shift[c];
    const float* row = cinh + (size_t)(b * OINH + c) * TOUT;
    float v = 0.f;
    for (int t = 0; t < TOUT; ++t) {
        float xin = row[t] * sc + sh;
        v = 0.5f * v + xin;
        unsigned char s = (v >= 1.f) ? 1 : 0;
        spk[((size_t)t * BB + b) * OINH + c] = s;
        v = (v >= 1.f) ? 0.f : v;
    }
}

// ---------------------------------------------------------------------------
// out[b,o,t] += sum_c spk[t,b,c] * wt[c,o]
// ---------------------------------------------------------------------------
__global__ __launch_bounds__(256)
void finale(const unsigned char* __restrict__ spk, const float* __restrict__ wt,
            float* __restrict__ out) {
    __shared__ float s_lds[64 * 129];
    const int tid = threadIdx.x;
    const int tx = tid & 15, ty = tid >> 4;
    const int b = blockIdx.z, t0 = blockIdx.x * 64, o0 = blockIdx.y * 64;

#pragma unroll
    for (int s = 0; s < 32; ++s) {
        int f = tid + s * 256;
        int tt = f >> 7, c = f & 127;
        float v = 0.f;
        if (t0 + tt < TOUT) v = (float)spk[((size_t)(t0 + tt) * BB + b) * OINH + c];
        s_lds[tt * 129 + c] = v;
    }
    __syncthreads();

    float acc[4][4] = {{0.f}};
#pragma unroll 4
    for (int c = 0; c < 128; ++c) {
        float4 wv = *(const float4*)(wt + c * OEXC + o0 + ty * 4);
        float wvv[4] = {wv.x, wv.y, wv.z, wv.w};
        float sv[4];
#pragma unroll
        for (int rt = 0; rt < 4; ++rt) sv[rt] = s_lds[(tx * 4 + rt) * 129 + c];
#pragma unroll
        for (int ro = 0; ro < 4; ++ro)
#pragma unroll
            for (int rt = 0; rt < 4; ++rt)
                acc[ro][rt] += wvv[ro] * sv[rt];
    }

    const int tvalid = TOUT - t0;
    if (tx * 4 < tvalid) {
#pragma unroll
        for (int ro = 0; ro < 4; ++ro) {
            float* op = out + (size_t)(b * OEXC + o0 + ty * 4 + ro) * TOUT + t0 + tx * 4;
            float4 v = *(float4*)op;
            v.x += acc[ro][0]; v.y += acc[ro][1]; v.z += acc[ro][2]; v.w += acc[ro][3];
            *(float4*)op = v;
        }
    }
}

// ---------------------------------------------------------------------------
extern "C" void kernel_launch(void* const* d_in, const int* in_sizes, int n_in,
                              void* d_out, int out_size, void* d_ws, size_t ws_size,
                              hipStream_t stream) {
    const float* x       = (const float*)d_in[0];
    const float* W_inh   = (const float*)d_in[1];
    const float* P_inh   = (const float*)d_in[2];
    const float* SIG_inh = (const float*)d_in[3];
    const float* W_exc   = (const float*)d_in[4];
    const float* P_exc   = (const float*)d_in[5];
    const float* SIG_exc = (const float*)d_in[6];
    const float* w_ei    = (const float*)d_in[7];
    const float* gamma   = (const float*)d_in[8];
    const float* beta    = (const float*)d_in[9];
    float* out = (float*)d_out;

    const size_t XT_ELEMS  = (size_t)BB * TROWS * IPAD;     // 14,057,472
    const size_t KEXC_ELEMS = (size_t)DD * OEXC * IPAD;     //  4,505,600
    const size_t KINH_ELEMS = (size_t)DD * OINH * IPAD;     //  2,252,800
    const size_t CINH_ELEMS = (size_t)BB * OINH * TOUT;     //  2,260,992
    const size_t NEED_FAST = 2 * XT_ELEMS * 2 + KEXC_ELEMS * 2 + 2 * KINH_ELEMS * 2 +
                             CINH_ELEMS * 4 + OINH * OEXC * 4 + CINH_ELEMS;  // 85,688,320 B

    if (ws_size >= NEED_FAST) {
        // ---- fast path: both convs on MFMA (inh = split bf16 3-term) ----
        unsigned short* xTh = (unsigned short*)d_ws;
        unsigned short* xTl = xTh + XT_ELEMS;
        unsigned short* kb2 = xTl + XT_ELEMS;
        unsigned short* kbh = kb2 + KEXC_ELEMS;
        unsigned short* kbl = kbh + KINH_ELEMS;
        float* cinh  = (float*)(kbl + KINH_ELEMS);
        float* wt    = cinh + CINH_ELEMS;
        float* scale = wt + OINH * OEXC;
        float* shift = scale + OINH;
        unsigned char* spk = (unsigned char*)(shift + OINH);

        hipLaunchKernelGGL(kexc_build, dim3((OEXC * IPAD + 255) / 256), dim3(256), 0, stream,
                           W_exc, P_exc, SIG_exc, kb2);
        hipLaunchKernelGGL(kinh_build, dim3((OINH * IPAD + 255) / 256), dim3(256), 0, stream,
                           W_inh, P_inh, SIG_inh, kbh, kbl);
        hipLaunchKernelGGL(xt_kernel, dim3(5, 11, 64), dim3(256), 0, stream, x, xTh, xTl);
        hipLaunchKernelGGL(wt_kernel, dim3(128), dim3(256), 0, stream, w_ei, wt);

        hipLaunchKernelGGL(conv_mfma, dim3(3, 2, 64), dim3(128), 0, stream, xTh, kb2, out);
        hipLaunchKernelGGL(conv_mfma_inh, dim3(3, 2, 64), dim3(128), 0, stream,
                           xTh, xTl, kbh, kbl, cinh);

        hipLaunchKernelGGL(bn_stats,   dim3(128), dim3(256), 0, stream, cinh, gamma, beta, scale, shift);
        hipLaunchKernelGGL(lif_kernel, dim3(64),  dim3(128), 0, stream, cinh, scale, shift, spk);
        hipLaunchKernelGGL(finale,     dim3(5, 4, 64), dim3(256), 0, stream, spk, wt, out);
    } else {
        // ---- fallback: round-3 configuration (inh conv in fp32) ----
        unsigned short* xTh = (unsigned short*)d_ws;
        unsigned short* kb2 = xTh + XT_ELEMS;
        float* kt_inh = (float*)(kb2 + KEXC_ELEMS);           // 2,240,000 f
        float* cinh   = kt_inh + 2240000;
        float* wt     = cinh + CINH_ELEMS;
        float* scale  = wt + OINH * OEXC;
        float* shift  = scale + OINH;
        unsigned char* spk = (unsigned char*)(shift + OINH);

        hipLaunchKernelGGL(kexc_build, dim3((OEXC * IPAD + 255) / 256), dim3(256), 0, stream,
                           W_exc, P_exc, SIG_exc, kb2);
        hipLaunchKernelGGL(build_kt, dim3(350), dim3(256), 0, stream,
                           W_inh, P_inh, SIG_inh, kt_inh, OINH);
        hipLaunchKernelGGL(xt_kernel, dim3(5, 11, 64), dim3(256), 0, stream, x, xTh,
                           (unsigned short*)nullptr);
        hipLaunchKernelGGL(wt_kernel, dim3(128), dim3(256), 0, stream, w_ei, wt);

        hipLaunchKernelGGL(conv_mfma, dim3(3, 2, 64), dim3(128), 0, stream, xTh, kb2, out);
        hipLaunchKernelGGL(conv_dcls, dim3(5, 1, 64), dim3(256), 0, stream, x, kt_inh, cinh, OINH);

        hipLaunchKernelGGL(bn_stats,   dim3(128), dim3(256), 0, stream, cinh, gamma, beta, scale, shift);
        hipLaunchKernelGGL(lif_kernel, dim3(64),  dim3(128), 0, stream, cinh, scale, shift, spk);
        hipLaunchKernelGGL(finale,     dim3(5, 4, 64), dim3(256), 0, stream, spk, wt, out);
    }
}

// Round 6
// 548.154 us; speedup vs baseline: 8.4332x; 1.1570x over previous
//
#include <hip/hip_runtime.h>
#include <math.h>

#define CI   700
#define TIN  300
#define DD   25
#define TOUT 276
#define BB   64
#define OINH 128
#define OEXC 256

#define TROWS 312          // padded t-rows in xT
#define IPAD  704          // channels padded to 22*32

typedef __attribute__((ext_vector_type(8))) short short8;
typedef __attribute__((ext_vector_type(4))) float f32x4;
typedef __attribute__((ext_vector_type(8))) unsigned short ushort8v;

static __device__ __forceinline__ unsigned short f2bf(float f) {
    unsigned int u = __float_as_uint(f);
    unsigned int r = (u + 0x7FFFu + ((u >> 16) & 1u)) >> 16;   // RNE
    return (unsigned short)r;
}
static __device__ __forceinline__ float bf2f(unsigned short h) {
    return __uint_as_float(((unsigned int)h) << 16);
}

static __device__ __forceinline__ void gload_lds16(const void* g, void* l) {
    __builtin_amdgcn_global_load_lds(
        (const __attribute__((address_space(1))) unsigned int*)g,
        (__attribute__((address_space(3))) unsigned int*)l, 16, 0, 0);
}

// ---------------------------------------------------------------------------
// Fallback inh path: fp32 DCLS kernel, layout kt[(i*25+d)*OINH + o]
// ---------------------------------------------------------------------------
__global__ void build_kt(const float* __restrict__ W, const float* __restrict__ P,
                         const float* __restrict__ SIG, float* __restrict__ kt, int O) {
    int n = blockIdx.x * 256 + threadIdx.x;
    if (n >= O * CI) return;
    int o = n % O;
    int i = n / O;
    float w   = fabsf(W[o * CI + i]);
    float p   = fminf(fmaxf(P[o * CI + i], -12.f), 12.f) + 12.f;
    float sig = fabsf(SIG[o * CI + i]) + 0.27f;
    float inv = 1.f / sig;
    float g[DD];
    float sum = 0.f;
#pragma unroll
    for (int d = 0; d < DD; ++d) {
        float e = ((float)d - p) * inv;
        g[d] = expf(-0.5f * e * e);
        sum += g[d];
    }
    float sc = w / (sum + 1e-7f);
#pragma unroll
    for (int d = 0; d < DD; ++d)
        kt[(i * DD + d) * O + o] = g[d] * sc;
}

// ---------------------------------------------------------------------------
// Exc path: bf16 DCLS kernel (hi only), layout kb2[d][o][ipad]
// ---------------------------------------------------------------------------
__global__ void kexc_build(const float* __restrict__ W, const float* __restrict__ P,
                           const float* __restrict__ SIG, unsigned short* __restrict__ kb2) {
    int n = blockIdx.x * 256 + threadIdx.x;           // n = o*IPAD + ip
    if (n >= OEXC * IPAD) return;
    int o = n / IPAD, ip = n % IPAD;
    if (ip >= CI) {
#pragma unroll
        for (int d = 0; d < DD; ++d)
            kb2[((size_t)d * OEXC + o) * IPAD + ip] = 0;
        return;
    }
    float w   = fabsf(W[o * CI + ip]);
    float p   = fminf(fmaxf(P[o * CI + ip], -12.f), 12.f) + 12.f;
    float sig = fabsf(SIG[o * CI + ip]) + 0.27f;
    float inv = 1.f / sig;
    float g[DD];
    float sum = 0.f;
#pragma unroll
    for (int d = 0; d < DD; ++d) {
        float e = ((float)d - p) * inv;
        g[d] = expf(-0.5f * e * e);
        sum += g[d];
    }
    float sc = w / (sum + 1e-7f);
#pragma unroll
    for (int d = 0; d < DD; ++d)
        kb2[((size_t)d * OEXC + o) * IPAD + ip] = f2bf(g[d] * sc);
}

// ---------------------------------------------------------------------------
// Inh path (fast): split bf16 hi/lo DCLS kernel, layout [d][o][ipad] x2
// ---------------------------------------------------------------------------
__global__ void kinh_build(const float* __restrict__ W, const float* __restrict__ P,
                           const float* __restrict__ SIG,
                           unsigned short* __restrict__ kbh, unsigned short* __restrict__ kbl) {
    int n = blockIdx.x * 256 + threadIdx.x;           // n = o*IPAD + ip
    if (n >= OINH * IPAD) return;
    int o = n / IPAD, ip = n % IPAD;
    if (ip >= CI) {
#pragma unroll
        for (int d = 0; d < DD; ++d) {
            kbh[((size_t)d * OINH + o) * IPAD + ip] = 0;
            kbl[((size_t)d * OINH + o) * IPAD + ip] = 0;
        }
        return;
    }
    float w   = fabsf(W[o * CI + ip]);
    float p   = fminf(fmaxf(P[o * CI + ip], -12.f), 12.f) + 12.f;
    float sig = fabsf(SIG[o * CI + ip]) + 0.27f;
    float inv = 1.f / sig;
    float g[DD];
    float sum = 0.f;
#pragma unroll
    for (int d = 0; d < DD; ++d) {
        float e = ((float)d - p) * inv;
        g[d] = expf(-0.5f * e * e);
        sum += g[d];
    }
    float sc = w / (sum + 1e-7f);
#pragma unroll
    for (int d = 0; d < DD; ++d) {
        float v = g[d] * sc;
        unsigned short h = f2bf(v);
        kbh[((size_t)d * OINH + o) * IPAD + ip] = h;
        kbl[((size_t)d * OINH + o) * IPAD + ip] = f2bf(v - bf2f(h));
    }
}

// ---------------------------------------------------------------------------
// xT[b][t][ipad] bf16 hi (+optional lo) = x[b][i][t]. LDS transpose, 64x64.
// grid (5 tchunks, 11 ichunks, 64 b).
// ---------------------------------------------------------------------------
__global__ __launch_bounds__(256)
void xt_kernel(const float* __restrict__ x, unsigned short* __restrict__ xTh,
               unsigned short* __restrict__ xTl) {
    __shared__ float tile[64][65];
    const int tid = threadIdx.x;
    const int t0 = blockIdx.x * 64, i0 = blockIdx.y * 64, b = blockIdx.z;
#pragma unroll
    for (int s = 0; s < 16; ++s) {
        int f = s * 256 + tid;
        int tt = f & 63, ii = f >> 6;
        float v = 0.f;
        if (t0 + tt < TIN && i0 + ii < CI)
            v = x[((size_t)b * CI + i0 + ii) * TIN + t0 + tt];
        tile[tt][ii] = v;
    }
    __syncthreads();
#pragma unroll
    for (int s = 0; s < 2; ++s) {
        int f = s * 256 + tid;
        int tt = f >> 3, g = f & 7;
        if (t0 + tt < TROWS) {
            ushort8v vh, vl;
#pragma unroll
            for (int e = 0; e < 8; ++e) {
                float v = tile[tt][g * 8 + e];
                unsigned short h = f2bf(v);
                vh[e] = h;
                vl[e] = f2bf(v - bf2f(h));
            }
            size_t off = ((size_t)b * TROWS + t0 + tt) * IPAD + i0 + g * 8;
            *(ushort8v*)(xTh + off) = vh;
            if (xTl) *(ushort8v*)(xTl + off) = vl;
        }
    }
}

// ---------------------------------------------------------------------------
// wt[c*256 + o] = -|w[o*128 + c]|
// ---------------------------------------------------------------------------
__global__ void wt_kernel(const float* __restrict__ w, float* __restrict__ wt) {
    int n = blockIdx.x * 256 + threadIdx.x;
    if (n >= OINH * OEXC) return;
    int o = n % OEXC, c = n / OEXC;
    wt[c * OEXC + o] = -fabsf(w[o * OINH + c]);
}

// ===========================================================================
// FUSED conv (fast2 path): both convs, 32-channel K-chunks, K-split x2.
// grid (6, 4, 64), 128 thr = 2 waves.
//   blockIdx.x: tt = x%3 (t0 = tt*96), ksp = x/3 (channel chunks [11ksp,11ksp+11))
//   blockIdx.y: 0,1 = exc (o0 = y*128 + wave*64); 2,3 = inh (o0 = (y-2)*64)
// LDS union 32 KB. Swizzle: 64B rows of 4x16B slots; slot ^= (row>>1)&3,
// applied on the global source at stage time (linear LDS dest) and on reads.
// ===========================================================================
__global__ __launch_bounds__(128)
void conv_fused32(const unsigned short* __restrict__ xTh, const unsigned short* __restrict__ xTl,
                  const unsigned short* __restrict__ kb2,
                  const unsigned short* __restrict__ kbh, const unsigned short* __restrict__ kbl,
                  float* __restrict__ pexc0, float* __restrict__ pexc1,
                  float* __restrict__ pinh0, float* __restrict__ pinh1) {
    __shared__ unsigned short lds[16384];          // 32 KB union

    const int tid  = threadIdx.x;
    const int wave = tid >> 6;
    const int lane = tid & 63;
    const int l15 = lane & 15, l4 = lane >> 4;
    const int tt   = blockIdx.x % 3;
    const int ksp  = blockIdx.x / 3;
    const int role = blockIdx.y;
    const int b    = blockIdx.z;
    const int t0   = tt * 96;
    const int icb  = ksp * 11;                     // 32-ch chunk base

    // staging lane constants: row r = lane>>2 in each 16-row issue, slot = lane&3
    const int ld_r = lane >> 2;
    const int ld_c = (((lane & 3) ^ ((lane >> 3) & 3)) << 4);  // swizzled src slot
    const int SA   = (l15 >> 1) & 3;               // read swizzle for rows i*16+l15

    const size_t xstride = (size_t)IPAD * 2;       // bytes per row (x and k)
    const char* xh_base = (const char*)xTh + ((size_t)b * TROWS + t0) * xstride;
    const char* xl_base = (const char*)xTl + ((size_t)b * TROWS + t0) * xstride;

    if (role < 2) {
        // ======================= EXC (1-term bf16) =======================
        unsigned short* xs = lds;                  // 128 rows x 32ch = 4096 sh
        unsigned short* ks = lds + 4096;           // [buf2][wave2][64x32=2048]
        const int o0 = role * 128 + wave * 64;

        f32x4 acc[4][6];
#pragma unroll
        for (int i = 0; i < 4; ++i)
#pragma unroll
            for (int j = 0; j < 6; ++j) acc[i][j] = (f32x4)0.f;

        for (int c = 0; c < 11; ++c) {
            const size_t cb = (size_t)(icb + c) * 64;
            __syncthreads();                       // xs/ks about to be reused
            for (int j = wave; j < 8; j += 2)
                gload_lds16(xh_base + (size_t)(16 * j + ld_r) * xstride + cb + ld_c,
                            (char*)xs + j * 1024);
            {
                const char* kbase = (const char*)kb2 + (size_t)o0 * xstride + cb;
                char* kdst = (char*)(ks + wave * 2048);
#pragma unroll
                for (int j = 0; j < 4; ++j)
                    gload_lds16(kbase + (size_t)(16 * j + ld_r) * xstride + ld_c,
                                kdst + j * 1024);
            }
            asm volatile("s_waitcnt vmcnt(0)" ::: "memory");
            __syncthreads();

            for (int d = 0; d < DD; ++d) {
                const int cur = d & 1;
                if (d < DD - 1) {                  // prefetch next-d k (own half)
                    const char* kbase = (const char*)kb2 +
                        ((size_t)((d + 1) * OEXC) + o0) * xstride + cb;
                    char* kdst = (char*)(ks + ((cur ^ 1) * 2 + wave) * 2048);
#pragma unroll
                    for (int j = 0; j < 4; ++j)
                        gload_lds16(kbase + (size_t)(16 * j + ld_r) * xstride + ld_c,
                                    kdst + j * 1024);
                }
                const char* kp = (const char*)(ks + (cur * 2 + wave) * 2048);
                short8 A[4];
#pragma unroll
                for (int i = 0; i < 4; ++i)
                    A[i] = *(const short8*)(kp + (i * 16 + l15) * 64 + ((l4 ^ SA) << 4));
#pragma unroll
                for (int j = 0; j < 6; ++j) {
                    const int tr = j * 16 + l15 + d;
                    short8 Bv = *(const short8*)((const char*)xs + tr * 64 +
                                                 ((l4 ^ ((tr >> 1) & 3)) << 4));
#pragma unroll
                    for (int i = 0; i < 4; ++i)
                        acc[i][j] = __builtin_amdgcn_mfma_f32_16x16x32_bf16(
                            A[i], Bv, acc[i][j], 0, 0, 0);
                }
                asm volatile("s_waitcnt vmcnt(0)" ::: "memory");
                // no per-d barrier: each wave reads only its own ks half
            }
        }
        float* dst = ksp ? pexc1 : pexc0;
#pragma unroll
        for (int i = 0; i < 4; ++i)
#pragma unroll
            for (int j = 0; j < 6; ++j) {
                const int t = t0 + j * 16 + l15;
                if (t < TOUT) {
                    float* op = dst + ((size_t)b * OEXC + o0 + i * 16 + l4 * 4) * TOUT + t;
#pragma unroll
                    for (int r = 0; r < 4; ++r) op[(size_t)r * TOUT] = acc[i][j][r];
                }
            }
    } else {
        // =================== INH (split bf16, 3-term) ===================
        unsigned short* xsh = lds;                 // 4096
        unsigned short* xsl = lds + 4096;          // 4096
        unsigned short* ksh = lds + 8192;          // [2][2048]
        unsigned short* ksl = lds + 12288;         // [2][2048]
        const int o0  = (role - 2) * 64;
        const int wtb = wave * 48;                 // wave t sub-base

        f32x4 acc[4][3];
#pragma unroll
        for (int i = 0; i < 4; ++i)
#pragma unroll
            for (int j = 0; j < 3; ++j) acc[i][j] = (f32x4)0.f;

        const unsigned short* kb = wave ? kbl : kbh;

        for (int c = 0; c < 11; ++c) {
            const size_t cb = (size_t)(icb + c) * 64;
            __syncthreads();
            for (int j = wave; j < 8; j += 2) {
                gload_lds16(xh_base + (size_t)(16 * j + ld_r) * xstride + cb + ld_c,
                            (char*)xsh + j * 1024);
                gload_lds16(xl_base + (size_t)(16 * j + ld_r) * xstride + cb + ld_c,
                            (char*)xsl + j * 1024);
            }
            {
                const char* kbase = (const char*)kb + (size_t)o0 * xstride + cb;
                char* kdst = (char*)((wave ? ksl : ksh));
#pragma unroll
                for (int j = 0; j < 4; ++j)
                    gload_lds16(kbase + (size_t)(16 * j + ld_r) * xstride + ld_c,
                                kdst + j * 1024);
            }
            asm volatile("s_waitcnt vmcnt(0)" ::: "memory");
            __syncthreads();

            for (int d = 0; d < DD; ++d) {
                const int cur = d & 1;
                if (d < DD - 1) {                  // wave0 -> ksh, wave1 -> ksl
                    const char* kbase = (const char*)kb +
                        ((size_t)((d + 1) * OINH) + o0) * xstride + cb;
                    char* kdst = (char*)((wave ? ksl : ksh) + (cur ^ 1) * 2048);
#pragma unroll
                    for (int j = 0; j < 4; ++j)
                        gload_lds16(kbase + (size_t)(16 * j + ld_r) * xstride + ld_c,
                                    kdst + j * 1024);
                }
                const char* kph = (const char*)(ksh + cur * 2048);
                const char* kpl = (const char*)(ksl + cur * 2048);
                short8 Ah[4], Al[4];
#pragma unroll
                for (int i = 0; i < 4; ++i) {
                    Ah[i] = *(const short8*)(kph + (i * 16 + l15) * 64 + ((l4 ^ SA) << 4));
                    Al[i] = *(const short8*)(kpl + (i * 16 + l15) * 64 + ((l4 ^ SA) << 4));
                }
#pragma unroll
                for (int j = 0; j < 3; ++j) {
                    const int tr = wtb + j * 16 + l15 + d;
                    const int xo = tr * 64 + ((l4 ^ ((tr >> 1) & 3)) << 4);
                    short8 Bh = *(const short8*)((const char*)xsh + xo);
                    short8 Bl = *(const short8*)((const char*)xsl + xo);
#pragma unroll
                    for (int i = 0; i < 4; ++i) {
                        acc[i][j] = __builtin_amdgcn_mfma_f32_16x16x32_bf16(
                            Ah[i], Bh, acc[i][j], 0, 0, 0);
                        acc[i][j] = __builtin_amdgcn_mfma_f32_16x16x32_bf16(
                            Ah[i], Bl, acc[i][j], 0, 0, 0);
                        acc[i][j] = __builtin_amdgcn_mfma_f32_16x16x32_bf16(
                            Al[i], Bh, acc[i][j], 0, 0, 0);
                    }
                }
                asm volatile("s_waitcnt vmcnt(0)" ::: "memory");
                __syncthreads();                   // cross-wave ksh/ksl handoff
            }
        }
        float* dst = ksp ? pinh1 : pinh0;
#pragma unroll
        for (int i = 0; i < 4; ++i)
#pragma unroll
            for (int j = 0; j < 3; ++j) {
                const int t = t0 + wtb + j * 16 + l15;
                if (t < TOUT) {
                    float* op = dst + ((size_t)b * OINH + o0 + i * 16 + l4 * 4) * TOUT + t;
#pragma unroll
                    for (int r = 0; r < 4; ++r) op[(size_t)r * TOUT] = acc[i][j][r];
                }
            }
    }
}

// ---------------------------------------------------------------------------
// out += pexc1 (K-split reduce for exc). float4, exact grid.
// ---------------------------------------------------------------------------
__global__ void add_exc(const float* __restrict__ p1, float* __restrict__ out) {
    int n = blockIdx.x * 256 + threadIdx.x;
    float4 a = ((const float4*)out)[n];
    float4 v = ((const float4*)p1)[n];
    a.x += v.x; a.y += v.y; a.z += v.z; a.w += v.w;
    ((float4*)out)[n] = a;
}

// ---------------------------------------------------------------------------
// BN stats fused with inh K-split reduce: cinh = cinh + q1, stats over (B,T').
// ---------------------------------------------------------------------------
__global__ void bn_stats2(float* __restrict__ cinh, const float* __restrict__ q1,
                          const float* __restrict__ gamma, const float* __restrict__ beta,
                          float* __restrict__ scale, float* __restrict__ shift) {
    const int c = blockIdx.x, tid = threadIdx.x;
    float sum = 0.f, sq = 0.f;
    for (int idx = tid; idx < BB * TOUT; idx += 256) {
        int b = idx / TOUT, t = idx - b * TOUT;
        size_t off = (size_t)(b * OINH + c) * TOUT + t;
        float v = cinh[off] + q1[off];
        cinh[off] = v;
        sum += v; sq += v * v;
    }
#pragma unroll
    for (int off = 32; off; off >>= 1) {
        sum += __shfl_down(sum, off);
        sq  += __shfl_down(sq, off);
    }
    __shared__ float ls[8];
    int wid = tid >> 6;
    if ((tid & 63) == 0) { ls[wid * 2] = sum; ls[wid * 2 + 1] = sq; }
    __syncthreads();
    if (tid == 0) {
        float S = 0.f, Q = 0.f;
#pragma unroll
        for (int wv = 0; wv < 4; ++wv) { S += ls[wv * 2]; Q += ls[wv * 2 + 1]; }
        const float n = (float)(BB * TOUT);
        float mean = S / n;
        float var  = Q / n - mean * mean;
        float rs   = 1.f / sqrtf(var + 1e-5f);
        float sc   = gamma[c] * rs;
        scale[c] = sc;
        shift[c] = beta[c] - mean * sc;
    }
}

// ---------------------------------------------------------------------------
// Round-4 fallback kernels (unchanged, known-good).
// ---------------------------------------------------------------------------
__global__ __launch_bounds__(128)
void conv_mfma(const unsigned short* __restrict__ xTh, const unsigned short* __restrict__ kb2,
               float* __restrict__ out) {
    __shared__ unsigned short xs[120 * 64];
    __shared__ unsigned short ks[2][2][64 * 64];

    const int tid  = threadIdx.x;
    const int wave = tid >> 6;
    const int lane = tid & 63;
    const int l15 = lane & 15, l4 = lane >> 4, l7 = lane & 7;
    const int b  = blockIdx.z;
    const int t0 = blockIdx.x * 96;
    const int o0 = blockIdx.y * 128 + wave * 64;

    const int ld_row = lane >> 3;
    const int ld_swz = ((l7 ^ ld_row) << 4);

    f32x4 acc[4][6];
#pragma unroll
    for (int i = 0; i < 4; ++i)
#pragma unroll
        for (int j = 0; j < 6; ++j) acc[i][j] = (f32x4)0.f;

    const char* xrow0 = (const char*)xTh + ((size_t)b * TROWS + t0) * (IPAD * 2);

    for (int ic = 0; ic < 11; ++ic) {
        const int ic0 = ic * 64;
        __syncthreads();
        for (int j = wave; j < 15; j += 2)
            gload_lds16(xrow0 + (size_t)(8 * j + ld_row) * (IPAD * 2) + ic0 * 2 + ld_swz,
                        (char*)xs + j * 1024);
        {
            const char* ksrc = (const char*)kb2 + ((size_t)o0) * (IPAD * 2) + ic0 * 2;
            char* kdst = (char*)ks + (0 * 2 + wave) * 8192;
#pragma unroll
            for (int j = 0; j < 8; ++j)
                gload_lds16(ksrc + (size_t)(8 * j + ld_row) * (IPAD * 2) + ld_swz,
                            kdst + j * 1024);
        }
        asm volatile("s_waitcnt vmcnt(0)" ::: "memory");
        __syncthreads();

        for (int d = 0; d < DD; ++d) {
            const int cur = d & 1;
            if (d < DD - 1) {
                const char* ksrc = (const char*)kb2 +
                    ((size_t)(d + 1) * OEXC + o0) * (IPAD * 2) + ic0 * 2;
                char* kdst = (char*)ks + ((cur ^ 1) * 2 + wave) * 8192;
#pragma unroll
                for (int j = 0; j < 8; ++j)
                    gload_lds16(ksrc + (size_t)(8 * j + ld_row) * (IPAD * 2) + ld_swz,
                                kdst + j * 1024);
            }
            const char* kp = (const char*)ks + (cur * 2 + wave) * 8192;
#pragma unroll
            for (int ks2 = 0; ks2 < 2; ++ks2) {
                const int cg = ks2 * 4 + l4;
                short8 A[4];
#pragma unroll
                for (int i = 0; i < 4; ++i)
                    A[i] = *(const short8*)(kp + (i * 16 + l15) * 128 + ((cg ^ l7) << 4));
#pragma unroll
                for (int j = 0; j < 6; ++j) {
                    const int tr = j * 16 + l15 + d;
                    short8 Bv = *(const short8*)((const char*)xs + tr * 128 +
                                                 ((cg ^ (tr & 7)) << 4));
#pragma unroll
                    for (int i = 0; i < 4; ++i)
                        acc[i][j] = __builtin_amdgcn_mfma_f32_16x16x32_bf16(
                            A[i], Bv, acc[i][j], 0, 0, 0);
                }
            }
            asm volatile("s_waitcnt vmcnt(0)" ::: "memory");
        }
    }

#pragma unroll
    for (int i = 0; i < 4; ++i)
#pragma unroll
        for (int j = 0; j < 6; ++j) {
            const int tt = t0 + j * 16 + l15;
            if (tt < TOUT) {
                float* op = out + ((size_t)b * OEXC + o0 + i * 16 + l4 * 4) * TOUT + tt;
#pragma unroll
                for (int r = 0; r < 4; ++r) op[(size_t)r * TOUT] = acc[i][j][r];
            }
        }
}

__global__ __launch_bounds__(128)
void conv_mfma_inh(const unsigned short* __restrict__ xTh, const unsigned short* __restrict__ xTl,
                   const unsigned short* __restrict__ kbh, const unsigned short* __restrict__ kbl,
                   float* __restrict__ cinh) {
    __shared__ unsigned short xsh[120 * 64];
    __shared__ unsigned short xsl[120 * 64];
    __shared__ unsigned short ksh[2][64 * 64];
    __shared__ unsigned short ksl[2][64 * 64];

    const int tid  = threadIdx.x;
    const int wave = tid >> 6;
    const int lane = tid & 63;
    const int l15 = lane & 15, l4 = lane >> 4, l7 = lane & 7;
    const int b  = blockIdx.z;
    const int t0 = blockIdx.x * 96;
    const int o0 = blockIdx.y * 64;
    const int wtb = wave * 48;

    const int ld_row = lane >> 3;
    const int ld_swz = ((l7 ^ ld_row) << 4);

    f32x4 acc[4][3];
#pragma unroll
    for (int i = 0; i < 4; ++i)
#pragma unroll
        for (int j = 0; j < 3; ++j) acc[i][j] = (f32x4)0.f;

    const char* xrh = (const char*)xTh + ((size_t)b * TROWS + t0) * (IPAD * 2);
    const char* xrl = (const char*)xTl + ((size_t)b * TROWS + t0) * (IPAD * 2);
    const unsigned short* kb = wave ? kbl : kbh;

    for (int ic = 0; ic < 11; ++ic) {
        const int ic0 = ic * 64;
        __syncthreads();
        for (int j = wave; j < 15; j += 2) {
            gload_lds16(xrh + (size_t)(8 * j + ld_row) * (IPAD * 2) + ic0 * 2 + ld_swz,
                        (char*)xsh + j * 1024);
            gload_lds16(xrl + (size_t)(8 * j + ld_row) * (IPAD * 2) + ic0 * 2 + ld_swz,
                        (char*)xsl + j * 1024);
        }
        {
            char* kd = wave ? (char*)ksl[0] : (char*)ksh[0];
#pragma unroll
            for (int j = 0; j < 8; ++j)
                gload_lds16((const char*)kb +
                                ((size_t)(0 * OINH + o0 + 8 * j + ld_row)) * (IPAD * 2) +
                                ic0 * 2 + ld_swz,
                            kd + j * 1024);
        }
        asm volatile("s_waitcnt vmcnt(0)" ::: "memory");
        __syncthreads();

        for (int d = 0; d < DD; ++d) {
            const int cur = d & 1;
            if (d < DD - 1) {
                char* kd = wave ? (char*)ksl[cur ^ 1] : (char*)ksh[cur ^ 1];
#pragma unroll
                for (int j = 0; j < 8; ++j)
                    gload_lds16((const char*)kb +
                                    ((size_t)((d + 1) * OINH + o0 + 8 * j + ld_row)) * (IPAD * 2) +
                                    ic0 * 2 + ld_swz,
                                kd + j * 1024);
            }
            const char* kph = (const char*)ksh[cur];
            const char* kpl = (const char*)ksl[cur];
#pragma unroll
            for (int k2 = 0; k2 < 2; ++k2) {
                const int cg = k2 * 4 + l4;
                short8 Ah[4], Al[4];
#pragma unroll
                for (int i = 0; i < 4; ++i) {
                    Ah[i] = *(const short8*)(kph + (i * 16 + l15) * 128 + ((cg ^ l7) << 4));
                    Al[i] = *(const short8*)(kpl + (i * 16 + l15) * 128 + ((cg ^ l7) << 4));
                }
#pragma unroll
                for (int j = 0; j < 3; ++j) {
                    const int tr = wtb + j * 16 + l15 + d;
                    short8 Bh = *(const short8*)((const char*)xsh + tr * 128 +
                                                 ((cg ^ (tr & 7)) << 4));
                    short8 Bl = *(const short8*)((const char*)xsl + tr * 128 +
                                                 ((cg ^ (tr & 7)) << 4));
#pragma unroll
                    for (int i = 0; i < 4; ++i) {
                        acc[i][j] = __builtin_amdgcn_mfma_f32_16x16x32_bf16(
                            Ah[i], Bh, acc[i][j], 0, 0, 0);
                        acc[i][j] = __builtin_amdgcn_mfma_f32_16x16x32_bf16(
                            Ah[i], Bl, acc[i][j], 0, 0, 0);
                        acc[i][j] = __builtin_amdgcn_mfma_f32_16x16x32_bf16(
                            Al[i], Bh, acc[i][j], 0, 0, 0);
                    }
                }
            }
            asm volatile("s_waitcnt vmcnt(0)" ::: "memory");
            __syncthreads();
        }
    }

#pragma unroll
    for (int i = 0; i < 4; ++i)
#pragma unroll
        for (int j = 0; j < 3; ++j) {
            const int tt = t0 + wtb + j * 16 + l15;
            if (tt < TOUT) {
                float* op = cinh + ((size_t)b * OINH + o0 + i * 16 + l4 * 4) * TOUT + tt;
#pragma unroll
                for (int r = 0; r < 4; ++r) op[(size_t)r * TOUT] = acc[i][j][r];
            }
        }
}

__global__ __launch_bounds__(256)
void conv_dcls(const float* __restrict__ x, const float* __restrict__ kt,
               float* __restrict__ out, int O) {
    __shared__ float k_lds[100 * 128];
    __shared__ float x_lds[4 * 88];

    const int tid = threadIdx.x;
    const int tx = tid & 7;
    const int ty = tid >> 3;
    const int b  = blockIdx.z;
    const int t0 = blockIdx.x * 64;
    const int o0 = blockIdx.y * 128;
    const int tlim = TIN - t0;

    float acc[4][8];
#pragma unroll
    for (int ro = 0; ro < 4; ++ro)
#pragma unroll
        for (int rt = 0; rt < 8; ++rt) acc[ro][rt] = 0.f;

    for (int chunk = 0; chunk < 175; ++chunk) {
        const int i0 = chunk * 4;
        __syncthreads();
#pragma unroll
        for (int s = 0; s < 13; ++s) {
            int f = tid + s * 256;
            if (f < 3200) {
                int j = f >> 5, o4 = f & 31;
                ((float4*)k_lds)[f] =
                    *(const float4*)(kt + (size_t)(i0 * DD + j) * O + o0 + o4 * 4);
            }
        }
        if (tid < 88) {
            int icc = tid / 22, wq = tid % 22;
            float4 v = make_float4(0.f, 0.f, 0.f, 0.f);
            if (wq * 4 < tlim)
                v = *(const float4*)(x + (size_t)(b * CI + i0 + icc) * TIN + t0 + wq * 4);
            ((float4*)x_lds)[tid] = v;
        }
        __syncthreads();
#pragma unroll
        for (int icc = 0; icc < 4; ++icc) {
            float xv[32];
#pragma unroll
            for (int wq = 0; wq < 8; ++wq)
                *(float4*)(xv + 4 * wq) = ((const float4*)(x_lds + icc * 88))[tx * 2 + wq];
#pragma unroll
            for (int d = 0; d < DD; ++d) {
                float4 kv = ((const float4*)(k_lds + (icc * DD + d) * 128))[ty];
                float kvv[4] = {kv.x, kv.y, kv.z, kv.w};
#pragma unroll
                for (int ro = 0; ro < 4; ++ro)
#pragma unroll
                    for (int rt = 0; rt < 8; ++rt)
                        acc[ro][rt] += kvv[ro] * xv[rt + d];
            }
        }
    }
    const int tvalid = TOUT - t0;
#pragma unroll
    for (int ro = 0; ro < 4; ++ro) {
        float* op = out + (size_t)(b * O + o0 + ty * 4 + ro) * TOUT + t0;
#pragma unroll
        for (int u = 0; u < 2; ++u) {
            int toff = tx * 8 + u * 4;
            if (toff < tvalid) {
                float4 v = make_float4(acc[ro][u * 4 + 0], acc[ro][u * 4 + 1],
                                       acc[ro][u * 4 + 2], acc[ro][u * 4 + 3]);
                *(float4*)(op + toff) = v;
            }
        }
    }
}

__global__ void bn_stats(const float* __restrict__ cinh, const float* __restrict__ gamma,
                         const float* __restrict__ beta, float* __restrict__ scale,
                         float* __restrict__ shift) {
    const int c = blockIdx.x, tid = threadIdx.x;
    float sum = 0.f, sq = 0.f;
    for (int idx = tid; idx < BB * TOUT; idx += 256) {
        int b = idx / TOUT, t = idx - b * TOUT;
        float v = cinh[(size_t)(b * OINH + c) * TOUT + t];
        sum += v; sq += v * v;
    }
#pragma unroll
    for (int off = 32; off; off >>= 1) {
        sum += __shfl_down(sum, off);
        sq  += __shfl_down(sq, off);
    }
    __shared__ float ls[8];
    int wid = tid >> 6;
    if ((tid & 63) == 0) { ls[wid * 2] = sum; ls[wid * 2 + 1] = sq; }
    __syncthreads();
    if (tid == 0) {
        float S = 0.f, Q = 0.f;
#pragma unroll
        for (int wv = 0; wv < 4; ++wv) { S += ls[wv * 2]; Q += ls[wv * 2 + 1]; }
        const float n = (float)(BB * TOUT);
        float mean = S / n;
        float var  = Q / n - mean * mean;
        float rs   = 1.f / sqrtf(var + 1e-5f);
        float sc   = gamma[c] * rs;
        scale[c] = sc;
        shift[c] = beta[c] - mean * sc;
    }
}

__global__ void lif_kernel(const float* __restrict__ cinh, const float* __restrict__ scale,
                           const float* __restrict__ shift, unsigned char* __restrict__ spk) {
    const int b = blockIdx.x, c = threadIdx.x;
    const float sc = scale[c], sh = shift[c];
    const float* row = cinh + (size_t)(b * OINH + c) * TOUT;
    float v = 0.f;
    for (int t = 0; t < TOUT; ++t) {
        float xin = row[t] * sc + sh;
        v = 0.5f * v + xin;
        unsigned char s = (v >= 1.f) ? 1 : 0;
        spk[((size_t)t * BB + b) * OINH + c] = s;
        v = (v >= 1.f) ? 0.f : v;
    }
}

__global__ __launch_bounds__(256)
void finale(const unsigned char* __restrict__ spk, const float* __restrict__ wt,
            float* __restrict__ out) {
    __shared__ float s_lds[64 * 129];
    const int tid = threadIdx.x;
    const int tx = tid & 15, ty = tid >> 4;
    const int b = blockIdx.z, t0 = blockIdx.x * 64, o0 = blockIdx.y * 64;

#pragma unroll
    for (int s = 0; s < 32; ++s) {
        int f = tid + s * 256;
        int tt = f >> 7, c = f & 127;
        float v = 0.f;
        if (t0 + tt < TOUT) v = (float)spk[((size_t)(t0 + tt) * BB + b) * OINH + c];
        s_lds[tt * 129 + c] = v;
    }
    __syncthreads();

    float acc[4][4] = {{0.f}};
#pragma unroll 4
    for (int c = 0; c < 128; ++c) {
        float4 wv = *(const float4*)(wt + c * OEXC + o0 + ty * 4);
        float wvv[4] = {wv.x, wv.y, wv.z, wv.w};
        float sv[4];
#pragma unroll
        for (int rt = 0; rt < 4; ++rt) sv[rt] = s_lds[(tx * 4 + rt) * 129 + c];
#pragma unroll
        for (int ro = 0; ro < 4; ++ro)
#pragma unroll
            for (int rt = 0; rt < 4; ++rt)
                acc[ro][rt] += wvv[ro] * sv[rt];
    }

    const int tvalid = TOUT - t0;
    if (tx * 4 < tvalid) {
#pragma unroll
        for (int ro = 0; ro < 4; ++ro) {
            float* op = out + (size_t)(b * OEXC + o0 + ty * 4 + ro) * TOUT + t0 + tx * 4;
            float4 v = *(float4*)op;
            v.x += acc[ro][0]; v.y += acc[ro][1]; v.z += acc[ro][2]; v.w += acc[ro][3];
            *(float4*)op = v;
        }
    }
}

// ---------------------------------------------------------------------------
extern "C" void kernel_launch(void* const* d_in, const int* in_sizes, int n_in,
                              void* d_out, int out_size, void* d_ws, size_t ws_size,
                              hipStream_t stream) {
    const float* x       = (const float*)d_in[0];
    const float* W_inh   = (const float*)d_in[1];
    const float* P_inh   = (const float*)d_in[2];
    const float* SIG_inh = (const float*)d_in[3];
    const float* W_exc   = (const float*)d_in[4];
    const float* P_exc   = (const float*)d_in[5];
    const float* SIG_exc = (const float*)d_in[6];
    const float* w_ei    = (const float*)d_in[7];
    const float* gamma   = (const float*)d_in[8];
    const float* beta    = (const float*)d_in[9];
    float* out = (float*)d_out;

    const size_t XT_ELEMS   = (size_t)BB * TROWS * IPAD;    // 14,057,472
    const size_t KEXC_ELEMS = (size_t)DD * OEXC * IPAD;     //  4,505,600
    const size_t KINH_ELEMS = (size_t)DD * OINH * IPAD;     //  2,252,800
    const size_t CINH_ELEMS = (size_t)BB * OINH * TOUT;     //  2,260,992
    const size_t PEXC_ELEMS = (size_t)BB * OEXC * TOUT;     //  4,521,984

    const size_t NEED_FAST = 2 * XT_ELEMS * 2 + KEXC_ELEMS * 2 + 2 * KINH_ELEMS * 2 +
                             CINH_ELEMS * 4 + OINH * OEXC * 4 + CINH_ELEMS;  // ~85.7 MB
    const size_t NEED_FAST2 = (2 * XT_ELEMS + KEXC_ELEMS + 2 * KINH_ELEMS) * 2 +
                              (PEXC_ELEMS + 2 * CINH_ELEMS + OINH * OEXC + 256) * 4 +
                              CINH_ELEMS;                                    // ~113 MB

    if (ws_size >= NEED_FAST2) {
        // ---- fast2: fused 32-chunk MFMA convs, K-split x2 ----
        unsigned short* xTh = (unsigned short*)d_ws;
        unsigned short* xTl = xTh + XT_ELEMS;
        unsigned short* kb2 = xTl + XT_ELEMS;
        unsigned short* kbh = kb2 + KEXC_ELEMS;
        unsigned short* kbl = kbh + KINH_ELEMS;
        float* pexc1 = (float*)(kbl + KINH_ELEMS);
        float* cinh  = pexc1 + PEXC_ELEMS;          // doubles as pinh0
        float* pinh1 = cinh + CINH_ELEMS;
        float* wt    = pinh1 + CINH_ELEMS;
        float* scale = wt + OINH * OEXC;
        float* shift = scale + OINH;
        unsigned char* spk = (unsigned char*)(shift + OINH);

        hipLaunchKernelGGL(kexc_build, dim3((OEXC * IPAD + 255) / 256), dim3(256), 0, stream,
                           W_exc, P_exc, SIG_exc, kb2);
        hipLaunchKernelGGL(kinh_build, dim3((OINH * IPAD + 255) / 256), dim3(256), 0, stream,
                           W_inh, P_inh, SIG_inh, kbh, kbl);
        hipLaunchKernelGGL(xt_kernel, dim3(5, 11, 64), dim3(256), 0, stream, x, xTh, xTl);
        hipLaunchKernelGGL(wt_kernel, dim3(128), dim3(256), 0, stream, w_ei, wt);

        hipLaunchKernelGGL(conv_fused32, dim3(6, 4, 64), dim3(128), 0, stream,
                           xTh, xTl, kb2, kbh, kbl, out, pexc1, cinh, pinh1);

        hipLaunchKernelGGL(add_exc, dim3((unsigned)(PEXC_ELEMS / 4 / 256)), dim3(256), 0, stream,
                           pexc1, out);
        hipLaunchKernelGGL(bn_stats2, dim3(128), dim3(256), 0, stream,
                           cinh, pinh1, gamma, beta, scale, shift);
        hipLaunchKernelGGL(lif_kernel, dim3(64), dim3(128), 0, stream, cinh, scale, shift, spk);
        hipLaunchKernelGGL(finale, dim3(5, 4, 64), dim3(256), 0, stream, spk, wt, out);
    } else if (ws_size >= NEED_FAST) {
        // ---- round-4 fast path (known good) ----
        unsigned short* xTh = (unsigned short*)d_ws;
        unsigned short* xTl = xTh + XT_ELEMS;
        unsigned short* kb2 = xTl + XT_ELEMS;
        unsigned short* kbh = kb2 + KEXC_ELEMS;
        unsigned short* kbl = kbh + KINH_ELEMS;
        float* cinh  = (float*)(kbl + KINH_ELEMS);
        float* wt    = cinh + CINH_ELEMS;
        float* scale = wt + OINH * OEXC;
        float* shift = scale + OINH;
        unsigned char* spk = (unsigned char*)(shift + OINH);

        hipLaunchKernelGGL(kexc_build, dim3((OEXC * IPAD + 255) / 256), dim3(256), 0, stream,
                           W_exc, P_exc, SIG_exc, kb2);
        hipLaunchKernelGGL(kinh_build, dim3((OINH * IPAD + 255) / 256), dim3(256), 0, stream,
                           W_inh, P_inh, SIG_inh, kbh, kbl);
        hipLaunchKernelGGL(xt_kernel, dim3(5, 11, 64), dim3(256), 0, stream, x, xTh, xTl);
        hipLaunchKernelGGL(wt_kernel, dim3(128), dim3(256), 0, stream, w_ei, wt);

        hipLaunchKernelGGL(conv_mfma, dim3(3, 2, 64), dim3(128), 0, stream, xTh, kb2, out);
        hipLaunchKernelGGL(conv_mfma_inh, dim3(3, 2, 64), dim3(128), 0, stream,
                           xTh, xTl, kbh, kbl, cinh);

        hipLaunchKernelGGL(bn_stats, dim3(128), dim3(256), 0, stream, cinh, gamma, beta, scale, shift);
        hipLaunchKernelGGL(lif_kernel, dim3(64), dim3(128), 0, stream, cinh, scale, shift, spk);
        hipLaunchKernelGGL(finale, dim3(5, 4, 64), dim3(256), 0, stream, spk, wt, out);
    } else {
        // ---- round-3 fallback (inh conv in fp32) ----
        unsigned short* xTh = (unsigned short*)d_ws;
        unsigned short* kb2 = xTh + XT_ELEMS;
        float* kt_inh = (float*)(kb2 + KEXC_ELEMS);
        float* cinh   = kt_inh + 2240000;
        float* wt     = cinh + CINH_ELEMS;
        float* scale  = wt + OINH * OEXC;
        float* shift  = scale + OINH;
        unsigned char* spk = (unsigned char*)(shift + OINH);

        hipLaunchKernelGGL(kexc_build, dim3((OEXC * IPAD + 255) / 256), dim3(256), 0, stream,
                           W_exc, P_exc, SIG_exc, kb2);
        hipLaunchKernelGGL(build_kt, dim3(350), dim3(256), 0, stream,
                           W_inh, P_inh, SIG_inh, kt_inh, OINH);
        hipLaunchKernelGGL(xt_kernel, dim3(5, 11, 64), dim3(256), 0, stream, x, xTh,
                           (unsigned short*)nullptr);
        hipLaunchKernelGGL(wt_kernel, dim3(128), dim3(256), 0, stream, w_ei, wt);

        hipLaunchKernelGGL(conv_mfma, dim3(3, 2, 64), dim3(128), 0, stream, xTh, kb2, out);
        hipLaunchKernelGGL(conv_dcls, dim3(5, 1, 64), dim3(256), 0, stream, x, kt_inh, cinh, OINH);

        hipLaunchKernelGGL(bn_stats, dim3(128), dim3(256), 0, stream, cinh, gamma, beta, scale, shift);
        hipLaunchKernelGGL(lif_kernel, dim3(64), dim3(128), 0, stream, cinh, scale, shift, spk);
        hipLaunchKernelGGL(finale, dim3(5, 4, 64), dim3(256), 0, stream, spk, wt, out);
    }
}